// Round 1
// baseline (22691.121 us; speedup 1.0000x reference)
//
#include <hip/hip_runtime.h>

#define NN 100000
#define NE 3200000
#define F 256
#define NCLS 40

// ---------------- degree / norm ----------------
__global__ void degrees_k(const int* __restrict__ src, const int* __restrict__ dst,
                          float* __restrict__ dout, float* __restrict__ din, int nE) {
    int i = blockIdx.x * blockDim.x + threadIdx.x;
    int stride = gridDim.x * blockDim.x;
    for (; i < nE; i += stride) {
        atomicAdd(&dout[src[i]], 1.0f);
        atomicAdd(&din[dst[i]], 1.0f);
    }
}

__global__ void norms_k(const float* __restrict__ dout, const float* __restrict__ din,
                        float* __restrict__ nout, float* __restrict__ nin, int n) {
    int i = blockIdx.x * blockDim.x + threadIdx.x;
    if (i < n) {
        nout[i] = rsqrtf(fmaxf(dout[i], 1.0f));
        nin[i]  = rsqrtf(fmaxf(din[i], 1.0f));
    }
}

// ---------------- scale: h = x * norm_out[row] ----------------
__global__ void scale_k(const float4* __restrict__ in, const float* __restrict__ norm,
                        float4* __restrict__ out, int n4) {
    int i = blockIdx.x * blockDim.x + threadIdx.x;
    if (i < n4) {
        float s = norm[i >> 6];   // 64 float4 per 256-float row
        float4 v = in[i];
        v.x *= s; v.y *= s; v.z *= s; v.w *= s;
        out[i] = v;
    }
}

// ---------------- aggregation, 256-wide: one wave per edge ----------------
__global__ void agg256_k(const int* __restrict__ src, const int* __restrict__ dst,
                         const float* __restrict__ h, float* __restrict__ agg, int nE) {
    int wid  = (blockIdx.x * blockDim.x + threadIdx.x) >> 6;
    int lane = threadIdx.x & 63;
    if (wid < nE) {
        int s = src[wid], d = dst[wid];
        const float4 v = *(const float4*)(h + (size_t)s * F + lane * 4);
        float* o = agg + (size_t)d * F + lane * 4;
        atomicAdd(o + 0, v.x);
        atomicAdd(o + 1, v.y);
        atomicAdd(o + 2, v.z);
        atomicAdd(o + 3, v.w);
    }
}

// ---------------- aggregation, 40-wide ----------------
__global__ void agg40_k(const int* __restrict__ src, const int* __restrict__ dst,
                        const float* __restrict__ h, float* __restrict__ agg, int nE) {
    int idx = blockIdx.x * blockDim.x + threadIdx.x;
    int total = nE * NCLS;          // 128,000,000 < 2^31
    if (idx < total) {
        int e = idx / NCLS;
        int f = idx - e * NCLS;
        atomicAdd(&agg[(size_t)dst[e] * NCLS + f], h[(size_t)src[e] * NCLS + f]);
    }
}

// ---------------- final epilogue: out = out*norm_in[row] + b2[col] ----------------
__global__ void final_k(float* __restrict__ out, const float* __restrict__ nin,
                        const float* __restrict__ b2, int n) {
    int i = blockIdx.x * blockDim.x + threadIdx.x;
    if (i < n) {
        int r = i / NCLS;
        int c = i - r * NCLS;
        out[i] = out[i] * nin[r] + b2[c];
    }
}

// ---------------- pad W2 [256][40] -> [256][64] ----------------
__global__ void padw2_k(const float* __restrict__ w2, float* __restrict__ w2p) {
    int i = blockIdx.x * blockDim.x + threadIdx.x;
    if (i < 256 * 64) {
        int r = i >> 6, c = i & 63;
        w2p[i] = (c < NCLS) ? w2[r * NCLS + c] : 0.0f;
    }
}

// ---------------- tiled fp32 GEMM: C[M,*] = A[M,256] @ B[256,*] ----------------
// EPI==1: C[row,col] = relu(acc*nin[row] + bias[col]) * nout[row], C row stride 256
// EPI==0: C[row,col] = acc, store only col < ncols_out, C row stride ncols_out
template <int EPI>
__global__ __launch_bounds__(256) void gemm_k(
        const float* __restrict__ A, const float* __restrict__ B,
        float* __restrict__ C, int M, int ldb, int ncols_out,
        const float* __restrict__ nin, const float* __restrict__ nout,
        const float* __restrict__ bias) {
    __shared__ float As[16][64];
    __shared__ float Bs[16][64];
    int tid = threadIdx.x;
    int tx = tid & 15, ty = tid >> 4;
    int row0 = blockIdx.x * 64, col0 = blockIdx.y * 64;
    float acc[4][4] = {};

    int am = tid >> 2;          // 0..63 : row within A tile
    int ak = (tid & 3) * 4;     // 0,4,8,12 : k within A tile
    int bk = tid >> 4;          // 0..15 : k within B tile
    int bn = (tid & 15) * 4;    // 0..60 : col within B tile

    for (int k0 = 0; k0 < 256; k0 += 16) {
        float4 av = make_float4(0.f, 0.f, 0.f, 0.f);
        int arow = row0 + am;
        if (arow < M) av = *(const float4*)(A + (size_t)arow * 256 + k0 + ak);
        As[ak + 0][am] = av.x;
        As[ak + 1][am] = av.y;
        As[ak + 2][am] = av.z;
        As[ak + 3][am] = av.w;

        float4 bv = *(const float4*)(B + (size_t)(k0 + bk) * ldb + col0 + bn);
        *(float4*)&Bs[bk][bn] = bv;
        __syncthreads();

#pragma unroll
        for (int kk = 0; kk < 16; kk++) {
            float a[4], b[4];
#pragma unroll
            for (int i = 0; i < 4; i++) a[i] = As[kk][ty * 4 + i];
#pragma unroll
            for (int j = 0; j < 4; j++) b[j] = Bs[kk][tx * 4 + j];
#pragma unroll
            for (int i = 0; i < 4; i++)
#pragma unroll
                for (int j = 0; j < 4; j++) acc[i][j] += a[i] * b[j];
        }
        __syncthreads();
    }

#pragma unroll
    for (int i = 0; i < 4; i++) {
        int row = row0 + ty * 4 + i;
        if (row < M) {
            if (EPI == 1) {
                float si = nin[row], so = nout[row];
#pragma unroll
                for (int j = 0; j < 4; j++) {
                    int col = col0 + tx * 4 + j;
                    float x = acc[i][j] * si + bias[col];
                    x = fmaxf(x, 0.0f) * so;
                    C[(size_t)row * 256 + col] = x;
                }
            } else {
#pragma unroll
                for (int j = 0; j < 4; j++) {
                    int col = col0 + tx * 4 + j;
                    if (col < ncols_out) C[(size_t)row * ncols_out + col] = acc[i][j];
                }
            }
        }
    }
}

extern "C" void kernel_launch(void* const* d_in, const int* in_sizes, int n_in,
                              void* d_out, int out_size, void* d_ws, size_t ws_size,
                              hipStream_t stream) {
    const float* features = (const float*)d_in[0];
    const int*   src      = (const int*)d_in[1];
    const int*   dst      = (const int*)d_in[2];
    const float* W0       = (const float*)d_in[3];
    const float* b0       = (const float*)d_in[4];
    const float* W1       = (const float*)d_in[5];
    const float* b1       = (const float*)d_in[6];
    const float* W2       = (const float*)d_in[7];
    const float* b2       = (const float*)d_in[8];
    float* out = (float*)d_out;

    // ---- workspace carve ----
    char* ws = (char*)d_ws;
    const size_t FEAT_BYTES = (size_t)NN * F * 4;         // 102,400,000
    float* tmp1 = (float*)(ws);                           // [NN,256]
    float* tmp2 = (float*)(ws + FEAT_BYTES);              // [NN,256]
    float* t3   = tmp2;                                   // [NN,40] aliases tmp2 (tmp2 consumed before t3 written)
    char* small = ws + 2 * FEAT_BYTES;
    const size_t SB = 401408;                             // 4096-aligned small buffer
    float* w2p      = (float*)(small);                    // 256*64 floats (65,536 B < SB)
    float* deg_out  = (float*)(small + 1 * SB);
    float* deg_in   = (float*)(small + 2 * SB);
    float* norm_out = (float*)(small + 3 * SB);
    float* norm_in  = (float*)(small + 4 * SB);

    // ---- degrees & norms ----
    hipMemsetAsync(deg_out, 0, NN * 4, stream);
    hipMemsetAsync(deg_in, 0, NN * 4, stream);
    degrees_k<<<2048, 256, 0, stream>>>(src, dst, deg_out, deg_in, NE);
    norms_k<<<(NN + 255) / 256, 256, 0, stream>>>(deg_out, deg_in, norm_out, norm_in, NN);

    // ---- layer 0 ----
    int n4 = NN * (F / 4);
    scale_k<<<(n4 + 255) / 256, 256, 0, stream>>>((const float4*)features, norm_out,
                                                  (float4*)tmp1, n4);
    hipMemsetAsync(tmp2, 0, FEAT_BYTES, stream);
    agg256_k<<<(NE + 3) / 4, 256, 0, stream>>>(src, dst, tmp1, tmp2, NE);
    {
        dim3 grid((NN + 63) / 64, 4);
        gemm_k<1><<<grid, 256, 0, stream>>>(tmp2, W0, tmp1, NN, 256, 256,
                                            norm_in, norm_out, b0);
    }

    // ---- layer 1 ----
    hipMemsetAsync(tmp2, 0, FEAT_BYTES, stream);
    agg256_k<<<(NE + 3) / 4, 256, 0, stream>>>(src, dst, tmp1, tmp2, NE);
    {
        dim3 grid((NN + 63) / 64, 4);
        gemm_k<1><<<grid, 256, 0, stream>>>(tmp2, W1, tmp1, NN, 256, 256,
                                            norm_in, norm_out, b1);
    }

    // ---- layer 2: W first (256->40), then aggregate ----
    padw2_k<<<64, 256, 0, stream>>>(W2, w2p);
    {
        dim3 grid((NN + 63) / 64, 1);
        gemm_k<0><<<grid, 256, 0, stream>>>(tmp1, w2p, t3, NN, 64, NCLS,
                                            nullptr, nullptr, nullptr);
    }
    hipMemsetAsync(out, 0, (size_t)NN * NCLS * 4, stream);
    {
        int total = NE * NCLS;
        agg40_k<<<(total + 255) / 256, 256, 0, stream>>>(src, dst, t3, out, NE);
    }
    final_k<<<(NN * NCLS + 255) / 256, 256, 0, stream>>>(out, norm_in, b2, NN * NCLS);
}

// Round 2
// 2157.406 us; speedup vs baseline: 10.5178x; 10.5178x over previous
//
#include <hip/hip_runtime.h>

#define NN 100000
#define NE 3200000
#define F 256
#define NCLS 40

// ---------------- degree counts (int) ----------------
__global__ void count_k(const int* __restrict__ src, const int* __restrict__ dst,
                        int* __restrict__ cnt_out, int* __restrict__ cnt_in, int nE) {
    int i = blockIdx.x * blockDim.x + threadIdx.x;
    int stride = gridDim.x * blockDim.x;
    for (; i < nE; i += stride) {
        atomicAdd(&cnt_out[src[i]], 1);
        atomicAdd(&cnt_in[dst[i]], 1);
    }
}

__global__ void norms_k(const int* __restrict__ cnt_out, const int* __restrict__ cnt_in,
                        float* __restrict__ nout, float* __restrict__ nin, int n) {
    int i = blockIdx.x * blockDim.x + threadIdx.x;
    if (i < n) {
        nout[i] = rsqrtf(fmaxf((float)cnt_out[i], 1.0f));
        nin[i]  = rsqrtf(fmaxf((float)cnt_in[i], 1.0f));
    }
}

// ---------------- exclusive scan of cnt_in -> row_ptr (3 kernels) ----------------
// scan1: per-block (1024 elems) exclusive scan + block sum
__global__ __launch_bounds__(256) void scan1_k(const int* __restrict__ cin,
                                               int* __restrict__ excl,
                                               int* __restrict__ bsum, int n) {
    __shared__ int sh[256];
    int t = threadIdx.x, b = blockIdx.x;
    int base = b * 1024 + t * 4;
    int v0 = (base + 0 < n) ? cin[base + 0] : 0;
    int v1 = (base + 1 < n) ? cin[base + 1] : 0;
    int v2 = (base + 2 < n) ? cin[base + 2] : 0;
    int v3 = (base + 3 < n) ? cin[base + 3] : 0;
    int sum = v0 + v1 + v2 + v3;
    sh[t] = sum;
    __syncthreads();
    for (int off = 1; off < 256; off <<= 1) {
        int x = (t >= off) ? sh[t - off] : 0;
        __syncthreads();
        sh[t] += x;
        __syncthreads();
    }
    int tex = sh[t] - sum;  // exclusive prefix for this thread
    if (base + 0 < n) excl[base + 0] = tex;
    if (base + 1 < n) excl[base + 1] = tex + v0;
    if (base + 2 < n) excl[base + 2] = tex + v0 + v1;
    if (base + 3 < n) excl[base + 3] = tex + v0 + v1 + v2;
    if (t == 255) bsum[b] = sh[255];
}

// scan2: serial exclusive scan of block sums (nb ~ 98, trivial)
__global__ void scan2_k(int* __restrict__ bsum, int nb) {
    int run = 0;
    for (int i = 0; i < nb; i++) { int v = bsum[i]; bsum[i] = run; run += v; }
}

// scan3: add block offset, write row_ptr and cursor copy
__global__ void scan3_k(const int* __restrict__ excl, const int* __restrict__ bsum,
                        int* __restrict__ row_ptr, int* __restrict__ cursor, int n) {
    int i = blockIdx.x * blockDim.x + threadIdx.x;
    if (i < n) {
        int v = excl[i] + bsum[i >> 10];
        row_ptr[i] = v;
        cursor[i] = v;
    }
    if (i == 0) row_ptr[n] = NE;
}

// ---------------- scatter edges into CSR (grouped by dst) ----------------
__global__ void scatter_k(const int* __restrict__ src, const int* __restrict__ dst,
                          int* __restrict__ cursor, int* __restrict__ csr_src, int nE) {
    int i = blockIdx.x * blockDim.x + threadIdx.x;
    int stride = gridDim.x * blockDim.x;
    for (; i < nE; i += stride) {
        int p = atomicAdd(&cursor[dst[i]], 1);
        csr_src[p] = src[i];
    }
}

// ---------------- CSR aggregation, 256-wide: one wave per node, no atomics ----------------
// SCALE=1: multiply each gathered row by nout[src] (used for layer 0 from raw features)
template <int SCALE>
__global__ __launch_bounds__(256) void agg256_csr_k(
        const int* __restrict__ row_ptr, const int* __restrict__ csr_src,
        const float* __restrict__ h, const float* __restrict__ nout,
        float* __restrict__ agg, int nN) {
    int node = (blockIdx.x * blockDim.x + threadIdx.x) >> 6;
    int lane = threadIdx.x & 63;
    if (node >= nN) return;
    int beg = row_ptr[node], end = row_ptr[node + 1];
    float4 acc0 = {0.f, 0.f, 0.f, 0.f}, acc1 = {0.f, 0.f, 0.f, 0.f};
    int e = beg;
    for (; e + 1 < end; e += 2) {
        int s0 = csr_src[e], s1 = csr_src[e + 1];
        float4 v0 = *(const float4*)(h + (size_t)s0 * F + lane * 4);
        float4 v1 = *(const float4*)(h + (size_t)s1 * F + lane * 4);
        float c0 = SCALE ? nout[s0] : 1.0f;
        float c1 = SCALE ? nout[s1] : 1.0f;
        acc0.x += v0.x * c0; acc0.y += v0.y * c0; acc0.z += v0.z * c0; acc0.w += v0.w * c0;
        acc1.x += v1.x * c1; acc1.y += v1.y * c1; acc1.z += v1.z * c1; acc1.w += v1.w * c1;
    }
    if (e < end) {
        int s0 = csr_src[e];
        float4 v0 = *(const float4*)(h + (size_t)s0 * F + lane * 4);
        float c0 = SCALE ? nout[s0] : 1.0f;
        acc0.x += v0.x * c0; acc0.y += v0.y * c0; acc0.z += v0.z * c0; acc0.w += v0.w * c0;
    }
    float4 r;
    r.x = acc0.x + acc1.x; r.y = acc0.y + acc1.y;
    r.z = acc0.z + acc1.z; r.w = acc0.w + acc1.w;
    *(float4*)(agg + (size_t)node * F + lane * 4) = r;
}

// ---------------- CSR aggregation, 64-wide (layer 2) + final epilogue ----------------
__global__ __launch_bounds__(256) void agg64_csr_k(
        const int* __restrict__ row_ptr, const int* __restrict__ csr_src,
        const float* __restrict__ t3, const float* __restrict__ nin,
        const float* __restrict__ b2, float* __restrict__ out, int nN) {
    int node = (blockIdx.x * blockDim.x + threadIdx.x) >> 6;
    int lane = threadIdx.x & 63;
    if (node >= nN) return;
    int beg = row_ptr[node], end = row_ptr[node + 1];
    float a0 = 0.f, a1 = 0.f;
    int e = beg;
    for (; e + 1 < end; e += 2) {
        int s0 = csr_src[e], s1 = csr_src[e + 1];
        a0 += t3[(size_t)s0 * 64 + lane];
        a1 += t3[(size_t)s1 * 64 + lane];
    }
    if (e < end) a0 += t3[(size_t)csr_src[e] * 64 + lane];
    if (lane < NCLS)
        out[(size_t)node * NCLS + lane] = (a0 + a1) * nin[node] + b2[lane];
}

// ---------------- pad W2 [256][40] -> [256][64] ----------------
__global__ void padw2_k(const float* __restrict__ w2, float* __restrict__ w2p) {
    int i = blockIdx.x * blockDim.x + threadIdx.x;
    if (i < 256 * 64) {
        int r = i >> 6, c = i & 63;
        w2p[i] = (c < NCLS) ? w2[r * NCLS + c] : 0.0f;
    }
}

// ---------------- tiled fp32 GEMM: C[M,*] = A[M,256] @ B[256,*] ----------------
// EPI==1: C[row,col] = relu(acc*nin[row] + bias[col]) * nout[row], C row stride 256
// EPI==0: C[row,col] = acc, C row stride ncols_out (=64 here, full tile stored)
template <int EPI>
__global__ __launch_bounds__(256) void gemm_k(
        const float* __restrict__ A, const float* __restrict__ B,
        float* __restrict__ C, int M, int ldb, int ncols_out,
        const float* __restrict__ nin, const float* __restrict__ nout,
        const float* __restrict__ bias) {
    __shared__ float As[16][64];
    __shared__ float Bs[16][64];
    int tid = threadIdx.x;
    int tx = tid & 15, ty = tid >> 4;
    int row0 = blockIdx.x * 64, col0 = blockIdx.y * 64;
    float acc[4][4] = {};

    int am = tid >> 2;          // 0..63 : row within A tile
    int ak = (tid & 3) * 4;     // 0,4,8,12 : k within A tile
    int bk = tid >> 4;          // 0..15 : k within B tile
    int bn = (tid & 15) * 4;    // 0..60 : col within B tile

    for (int k0 = 0; k0 < 256; k0 += 16) {
        float4 av = make_float4(0.f, 0.f, 0.f, 0.f);
        int arow = row0 + am;
        if (arow < M) av = *(const float4*)(A + (size_t)arow * 256 + k0 + ak);
        As[ak + 0][am] = av.x;
        As[ak + 1][am] = av.y;
        As[ak + 2][am] = av.z;
        As[ak + 3][am] = av.w;

        float4 bv = *(const float4*)(B + (size_t)(k0 + bk) * ldb + col0 + bn);
        *(float4*)&Bs[bk][bn] = bv;
        __syncthreads();

#pragma unroll
        for (int kk = 0; kk < 16; kk++) {
            float a[4], b[4];
#pragma unroll
            for (int i = 0; i < 4; i++) a[i] = As[kk][ty * 4 + i];
#pragma unroll
            for (int j = 0; j < 4; j++) b[j] = Bs[kk][tx * 4 + j];
#pragma unroll
            for (int i = 0; i < 4; i++)
#pragma unroll
                for (int j = 0; j < 4; j++) acc[i][j] += a[i] * b[j];
        }
        __syncthreads();
    }

#pragma unroll
    for (int i = 0; i < 4; i++) {
        int row = row0 + ty * 4 + i;
        if (row < M) {
            if (EPI == 1) {
                float si = nin[row], so = nout[row];
#pragma unroll
                for (int j = 0; j < 4; j++) {
                    int col = col0 + tx * 4 + j;
                    float x = acc[i][j] * si + bias[col];
                    x = fmaxf(x, 0.0f) * so;
                    C[(size_t)row * 256 + col] = x;
                }
            } else {
#pragma unroll
                for (int j = 0; j < 4; j++) {
                    int col = col0 + tx * 4 + j;
                    if (col < ncols_out) C[(size_t)row * ncols_out + col] = acc[i][j];
                }
            }
        }
    }
}

extern "C" void kernel_launch(void* const* d_in, const int* in_sizes, int n_in,
                              void* d_out, int out_size, void* d_ws, size_t ws_size,
                              hipStream_t stream) {
    const float* features = (const float*)d_in[0];
    const int*   src      = (const int*)d_in[1];
    const int*   dst      = (const int*)d_in[2];
    const float* W0       = (const float*)d_in[3];
    const float* b0       = (const float*)d_in[4];
    const float* W1       = (const float*)d_in[5];
    const float* b1       = (const float*)d_in[6];
    const float* W2       = (const float*)d_in[7];
    const float* b2       = (const float*)d_in[8];
    float* out = (float*)d_out;

    // ---- workspace carve ----
    char* ws = (char*)d_ws;
    const size_t FEAT_BYTES = (size_t)NN * F * 4;          // 102,400,000
    float* tmp1 = (float*)(ws);                            // [NN,256]
    float* tmp2 = (float*)(ws + FEAT_BYTES);               // [NN,256]; later aliased as t3 [NN,64]
    char* p = ws + 2 * FEAT_BYTES;
    int* csr_src = (int*)p;          p += (size_t)NE * 4;  // 12.8 MB
    const size_t SB = 4 * (NN + 256);                      // small buffer stride (~400 KB)
    int*   cnt_out = (int*)(p + 0 * SB);
    int*   cnt_in  = (int*)(p + 1 * SB);
    int*   excl    = (int*)(p + 2 * SB);
    int*   row_ptr = (int*)(p + 3 * SB);                   // NN+1 ints
    int*   cursor  = (int*)(p + 4 * SB);
    float* nout    = (float*)(p + 5 * SB);
    float* nin     = (float*)(p + 6 * SB);
    int*   bsum    = (int*)(p + 7 * SB);                   // 98 ints
    float* w2p     = (float*)(p + 8 * SB);                 // 256*64 floats (64 KB)

    const int NB = (NN + 1023) / 1024;                     // 98 scan blocks
    const int AGG_BLOCKS = (NN * 64 + 255) / 256;          // 25000: one wave per node

    // ---- CSR build + norms ----
    hipMemsetAsync(cnt_out, 0, NN * 4, stream);
    hipMemsetAsync(cnt_in, 0, NN * 4, stream);
    count_k<<<2048, 256, 0, stream>>>(src, dst, cnt_out, cnt_in, NE);
    norms_k<<<(NN + 255) / 256, 256, 0, stream>>>(cnt_out, cnt_in, nout, nin, NN);
    scan1_k<<<NB, 256, 0, stream>>>(cnt_in, excl, bsum, NN);
    scan2_k<<<1, 1, 0, stream>>>(bsum, NB);
    scan3_k<<<(NN + 255) / 256, 256, 0, stream>>>(excl, bsum, row_ptr, cursor, NN);
    scatter_k<<<2048, 256, 0, stream>>>(src, dst, cursor, csr_src, NE);

    // ---- layer 0: gather(features * nout) -> tmp2; gemm -> tmp1 ----
    agg256_csr_k<1><<<AGG_BLOCKS, 256, 0, stream>>>(row_ptr, csr_src, features, nout, tmp2, NN);
    {
        dim3 grid((NN + 63) / 64, 4);
        gemm_k<1><<<grid, 256, 0, stream>>>(tmp2, W0, tmp1, NN, 256, 256, nin, nout, b0);
    }

    // ---- layer 1: gather(tmp1) -> tmp2; gemm -> tmp1 ----
    agg256_csr_k<0><<<AGG_BLOCKS, 256, 0, stream>>>(row_ptr, csr_src, tmp1, nullptr, tmp2, NN);
    {
        dim3 grid((NN + 63) / 64, 4);
        gemm_k<1><<<grid, 256, 0, stream>>>(tmp2, W1, tmp1, NN, 256, 256, nin, nout, b1);
    }

    // ---- layer 2: gemm (256->64 padded) -> t3; gather + epilogue -> out ----
    padw2_k<<<64, 256, 0, stream>>>(W2, w2p);
    float* t3 = tmp2;  // [NN,64], tmp2 free after gemm1 consumed it
    {
        dim3 grid((NN + 63) / 64, 1);
        gemm_k<0><<<grid, 256, 0, stream>>>(tmp1, w2p, t3, NN, 64, 64,
                                            nullptr, nullptr, nullptr);
    }
    agg64_csr_k<<<AGG_BLOCKS, 256, 0, stream>>>(row_ptr, csr_src, t3, nin, b2, out, NN);
}

// Round 3
// 2133.438 us; speedup vs baseline: 10.6359x; 1.0112x over previous
//
#include <hip/hip_runtime.h>

#define NN 100000
#define NE 3200000
#define F 256
#define NCLS 40

// ---------------- degree counts (int) ----------------
__global__ void count_k(const int* __restrict__ src, const int* __restrict__ dst,
                        int* __restrict__ cnt_out, int* __restrict__ cnt_in, int nE) {
    int i = blockIdx.x * blockDim.x + threadIdx.x;
    int stride = gridDim.x * blockDim.x;
    for (; i < nE; i += stride) {
        atomicAdd(&cnt_out[src[i]], 1);
        atomicAdd(&cnt_in[dst[i]], 1);
    }
}

__global__ void norms_k(const int* __restrict__ cnt_out, const int* __restrict__ cnt_in,
                        float* __restrict__ nout, float* __restrict__ nin, int n) {
    int i = blockIdx.x * blockDim.x + threadIdx.x;
    if (i < n) {
        nout[i] = rsqrtf(fmaxf((float)cnt_out[i], 1.0f));
        nin[i]  = rsqrtf(fmaxf((float)cnt_in[i], 1.0f));
    }
}

// ---------------- exclusive scan of cnt_in -> row_ptr (3 kernels) ----------------
__global__ __launch_bounds__(256) void scan1_k(const int* __restrict__ cin,
                                               int* __restrict__ excl,
                                               int* __restrict__ bsum, int n) {
    __shared__ int sh[256];
    int t = threadIdx.x, b = blockIdx.x;
    int base = b * 1024 + t * 4;
    int v0 = (base + 0 < n) ? cin[base + 0] : 0;
    int v1 = (base + 1 < n) ? cin[base + 1] : 0;
    int v2 = (base + 2 < n) ? cin[base + 2] : 0;
    int v3 = (base + 3 < n) ? cin[base + 3] : 0;
    int sum = v0 + v1 + v2 + v3;
    sh[t] = sum;
    __syncthreads();
    for (int off = 1; off < 256; off <<= 1) {
        int x = (t >= off) ? sh[t - off] : 0;
        __syncthreads();
        sh[t] += x;
        __syncthreads();
    }
    int tex = sh[t] - sum;
    if (base + 0 < n) excl[base + 0] = tex;
    if (base + 1 < n) excl[base + 1] = tex + v0;
    if (base + 2 < n) excl[base + 2] = tex + v0 + v1;
    if (base + 3 < n) excl[base + 3] = tex + v0 + v1 + v2;
    if (t == 255) bsum[b] = sh[255];
}

// scan2: parallel single-block scan of block sums (nb <= 128)
__global__ __launch_bounds__(128) void scan2_k(int* __restrict__ bsum, int nb) {
    __shared__ int sh[128];
    int t = threadIdx.x;
    int v = (t < nb) ? bsum[t] : 0;
    sh[t] = v;
    __syncthreads();
    for (int off = 1; off < 128; off <<= 1) {
        int x = (t >= off) ? sh[t - off] : 0;
        __syncthreads();
        sh[t] += x;
        __syncthreads();
    }
    if (t < nb) bsum[t] = sh[t] - v;   // exclusive
}

__global__ void scan3_k(const int* __restrict__ excl, const int* __restrict__ bsum,
                        int* __restrict__ row_ptr, int* __restrict__ cursor, int n) {
    int i = blockIdx.x * blockDim.x + threadIdx.x;
    if (i < n) {
        int v = excl[i] + bsum[i >> 10];
        row_ptr[i] = v;
        cursor[i] = v;
    }
    if (i == 0) row_ptr[n] = NE;
}

// ---------------- scatter edges into CSR (grouped by dst) ----------------
__global__ void scatter_k(const int* __restrict__ src, const int* __restrict__ dst,
                          int* __restrict__ cursor, int* __restrict__ csr_src, int nE) {
    int i = blockIdx.x * blockDim.x + threadIdx.x;
    int stride = gridDim.x * blockDim.x;
    for (; i < nE; i += stride) {
        int p = atomicAdd(&cursor[dst[i]], 1);
        csr_src[p] = src[i];
    }
}

// ---------------- CSR aggregation, 256-wide: one wave per node, 4-deep MLP ----------------
template <int SCALE>
__global__ __launch_bounds__(256) void agg256_csr_k(
        const int* __restrict__ row_ptr, const int* __restrict__ csr_src,
        const float* __restrict__ h, const float* __restrict__ nout,
        float* __restrict__ agg, int nN) {
    int node = (blockIdx.x * blockDim.x + threadIdx.x) >> 6;
    int lane = threadIdx.x & 63;
    if (node >= nN) return;
    int beg = row_ptr[node], end = row_ptr[node + 1];
    float4 acc0 = {0.f,0.f,0.f,0.f}, acc1 = {0.f,0.f,0.f,0.f};
    float4 acc2 = {0.f,0.f,0.f,0.f}, acc3 = {0.f,0.f,0.f,0.f};
    int e = beg;
    for (; e + 3 < end; e += 4) {
        int s0 = csr_src[e], s1 = csr_src[e+1], s2 = csr_src[e+2], s3 = csr_src[e+3];
        float4 v0 = *(const float4*)(h + (size_t)s0 * F + lane * 4);
        float4 v1 = *(const float4*)(h + (size_t)s1 * F + lane * 4);
        float4 v2 = *(const float4*)(h + (size_t)s2 * F + lane * 4);
        float4 v3 = *(const float4*)(h + (size_t)s3 * F + lane * 4);
        float c0 = SCALE ? nout[s0] : 1.0f;
        float c1 = SCALE ? nout[s1] : 1.0f;
        float c2 = SCALE ? nout[s2] : 1.0f;
        float c3 = SCALE ? nout[s3] : 1.0f;
        acc0.x += v0.x*c0; acc0.y += v0.y*c0; acc0.z += v0.z*c0; acc0.w += v0.w*c0;
        acc1.x += v1.x*c1; acc1.y += v1.y*c1; acc1.z += v1.z*c1; acc1.w += v1.w*c1;
        acc2.x += v2.x*c2; acc2.y += v2.y*c2; acc2.z += v2.z*c2; acc2.w += v2.w*c2;
        acc3.x += v3.x*c3; acc3.y += v3.y*c3; acc3.z += v3.z*c3; acc3.w += v3.w*c3;
    }
    for (; e < end; e++) {
        int s0 = csr_src[e];
        float4 v0 = *(const float4*)(h + (size_t)s0 * F + lane * 4);
        float c0 = SCALE ? nout[s0] : 1.0f;
        acc0.x += v0.x*c0; acc0.y += v0.y*c0; acc0.z += v0.z*c0; acc0.w += v0.w*c0;
    }
    float4 r;
    r.x = (acc0.x + acc1.x) + (acc2.x + acc3.x);
    r.y = (acc0.y + acc1.y) + (acc2.y + acc3.y);
    r.z = (acc0.z + acc1.z) + (acc2.z + acc3.z);
    r.w = (acc0.w + acc1.w) + (acc2.w + acc3.w);
    *(float4*)(agg + (size_t)node * F + lane * 4) = r;
}

// ---------------- CSR aggregation, 64-wide (layer 2) + final epilogue ----------------
__global__ __launch_bounds__(256) void agg64_csr_k(
        const int* __restrict__ row_ptr, const int* __restrict__ csr_src,
        const float* __restrict__ t3, const float* __restrict__ nin,
        const float* __restrict__ b2, float* __restrict__ out, int nN) {
    int node = (blockIdx.x * blockDim.x + threadIdx.x) >> 6;
    int lane = threadIdx.x & 63;
    if (node >= nN) return;
    int beg = row_ptr[node], end = row_ptr[node + 1];
    float a0 = 0.f, a1 = 0.f, a2 = 0.f, a3 = 0.f;
    int e = beg;
    for (; e + 3 < end; e += 4) {
        a0 += t3[(size_t)csr_src[e+0] * 64 + lane];
        a1 += t3[(size_t)csr_src[e+1] * 64 + lane];
        a2 += t3[(size_t)csr_src[e+2] * 64 + lane];
        a3 += t3[(size_t)csr_src[e+3] * 64 + lane];
    }
    for (; e < end; e++) a0 += t3[(size_t)csr_src[e] * 64 + lane];
    if (lane < NCLS)
        out[(size_t)node * NCLS + lane] = ((a0 + a1) + (a2 + a3)) * nin[node] + b2[lane];
}

// ---------------- pad W2 [256][40] -> [256][64] ----------------
__global__ void padw2_k(const float* __restrict__ w2, float* __restrict__ w2p) {
    int i = blockIdx.x * blockDim.x + threadIdx.x;
    if (i < 256 * 64) {
        int r = i >> 6, c = i & 63;
        w2p[i] = (c < NCLS) ? w2[r * NCLS + c] : 0.0f;
    }
}

// ---------------- big fp32 GEMM: C[M,256] = A[M,256] @ B[256,256], fused epilogue ----------------
// 128x128 tile, 8x8 per thread. C = relu(acc*nin[row] + bias[col]) * nout[row]
__global__ __launch_bounds__(256) void gemm128_k(
        const float* __restrict__ A, const float* __restrict__ B,
        float* __restrict__ C, int M,
        const float* __restrict__ nin, const float* __restrict__ nout,
        const float* __restrict__ bias) {
    __shared__ float As[16][128];
    __shared__ float Bs[16][128];
    int tid = threadIdx.x;
    int tx = tid & 15, ty = tid >> 4;
    int row0 = blockIdx.x * 128, col0 = blockIdx.y * 128;
    float acc[8][8] = {};

    for (int k0 = 0; k0 < 256; k0 += 16) {
#pragma unroll
        for (int l = 0; l < 2; l++) {
            int t = tid + l * 256;
            int r = t >> 2, g = t & 3;          // r 0..127, g 0..3
            int arow = row0 + r;
            float4 v = make_float4(0.f, 0.f, 0.f, 0.f);
            if (arow < M) v = *(const float4*)(A + (size_t)arow * 256 + k0 + g * 4);
            As[g * 4 + 0][r] = v.x;
            As[g * 4 + 1][r] = v.y;
            As[g * 4 + 2][r] = v.z;
            As[g * 4 + 3][r] = v.w;
        }
#pragma unroll
        for (int l = 0; l < 2; l++) {
            int t = tid + l * 256;
            int kk = t >> 5, c4 = t & 31;       // kk 0..15, c4 0..31
            float4 v = *(const float4*)(B + (size_t)(k0 + kk) * 256 + col0 + c4 * 4);
            *(float4*)&Bs[kk][c4 * 4] = v;
        }
        __syncthreads();

#pragma unroll
        for (int kk = 0; kk < 16; kk++) {
            float a[8], b[8];
            *(float4*)&a[0] = *(const float4*)&As[kk][ty * 4];
            *(float4*)&a[4] = *(const float4*)&As[kk][64 + ty * 4];
            *(float4*)&b[0] = *(const float4*)&Bs[kk][tx * 4];
            *(float4*)&b[4] = *(const float4*)&Bs[kk][64 + tx * 4];
#pragma unroll
            for (int i = 0; i < 8; i++)
#pragma unroll
                for (int j = 0; j < 8; j++) acc[i][j] += a[i] * b[j];
        }
        __syncthreads();
    }

#pragma unroll
    for (int i = 0; i < 8; i++) {
        int row = row0 + ((i < 4) ? (ty * 4 + i) : (64 + ty * 4 + (i - 4)));
        if (row < M) {
            float si = nin[row], so = nout[row];
            float4 o;
            int c0 = col0 + tx * 4;
            o.x = fmaxf(acc[i][0] * si + bias[c0 + 0], 0.f) * so;
            o.y = fmaxf(acc[i][1] * si + bias[c0 + 1], 0.f) * so;
            o.z = fmaxf(acc[i][2] * si + bias[c0 + 2], 0.f) * so;
            o.w = fmaxf(acc[i][3] * si + bias[c0 + 3], 0.f) * so;
            *(float4*)(C + (size_t)row * 256 + c0) = o;
            int c1 = col0 + 64 + tx * 4;
            o.x = fmaxf(acc[i][4] * si + bias[c1 + 0], 0.f) * so;
            o.y = fmaxf(acc[i][5] * si + bias[c1 + 1], 0.f) * so;
            o.z = fmaxf(acc[i][6] * si + bias[c1 + 2], 0.f) * so;
            o.w = fmaxf(acc[i][7] * si + bias[c1 + 3], 0.f) * so;
            *(float4*)(C + (size_t)row * 256 + c1) = o;
        }
    }
}

// ---------------- small fp32 GEMM: C[M,64] = A[M,256] @ B[256,64] (no epilogue) ----------------
__global__ __launch_bounds__(256) void gemm64_k(
        const float* __restrict__ A, const float* __restrict__ B,
        float* __restrict__ C, int M) {
    __shared__ float As[16][64];
    __shared__ float Bs[16][64];
    int tid = threadIdx.x;
    int tx = tid & 15, ty = tid >> 4;
    int row0 = blockIdx.x * 64;
    float acc[4][4] = {};

    int am = tid >> 2;
    int ak = (tid & 3) * 4;
    int bk = tid >> 4;
    int bn = (tid & 15) * 4;

    for (int k0 = 0; k0 < 256; k0 += 16) {
        float4 av = make_float4(0.f, 0.f, 0.f, 0.f);
        int arow = row0 + am;
        if (arow < M) av = *(const float4*)(A + (size_t)arow * 256 + k0 + ak);
        As[ak + 0][am] = av.x;
        As[ak + 1][am] = av.y;
        As[ak + 2][am] = av.z;
        As[ak + 3][am] = av.w;
        float4 bv = *(const float4*)(B + (size_t)(k0 + bk) * 64 + bn);
        *(float4*)&Bs[bk][bn] = bv;
        __syncthreads();
#pragma unroll
        for (int kk = 0; kk < 16; kk++) {
            float a[4], b[4];
#pragma unroll
            for (int i = 0; i < 4; i++) a[i] = As[kk][ty * 4 + i];
#pragma unroll
            for (int j = 0; j < 4; j++) b[j] = Bs[kk][tx * 4 + j];
#pragma unroll
            for (int i = 0; i < 4; i++)
#pragma unroll
                for (int j = 0; j < 4; j++) acc[i][j] += a[i] * b[j];
        }
        __syncthreads();
    }
#pragma unroll
    for (int i = 0; i < 4; i++) {
        int row = row0 + ty * 4 + i;
        if (row < M) {
#pragma unroll
            for (int j = 0; j < 4; j++)
                C[(size_t)row * 64 + tx * 4 + j] = acc[i][j];
        }
    }
}

extern "C" void kernel_launch(void* const* d_in, const int* in_sizes, int n_in,
                              void* d_out, int out_size, void* d_ws, size_t ws_size,
                              hipStream_t stream) {
    const float* features = (const float*)d_in[0];
    const int*   src      = (const int*)d_in[1];
    const int*   dst      = (const int*)d_in[2];
    const float* W0       = (const float*)d_in[3];
    const float* b0       = (const float*)d_in[4];
    const float* W1       = (const float*)d_in[5];
    const float* b1       = (const float*)d_in[6];
    const float* W2       = (const float*)d_in[7];
    const float* b2       = (const float*)d_in[8];
    float* out = (float*)d_out;

    // ---- workspace carve ----
    char* ws = (char*)d_ws;
    const size_t FEAT_BYTES = (size_t)NN * F * 4;          // 102,400,000
    float* tmp1 = (float*)(ws);                            // [NN,256]
    float* tmp2 = (float*)(ws + FEAT_BYTES);               // [NN,256]; later aliased as t3 [NN,64]
    char* p = ws + 2 * FEAT_BYTES;
    int* csr_src = (int*)p;          p += (size_t)NE * 4;  // 12.8 MB
    const size_t SB = 4 * (NN + 256);
    int*   cnt_out = (int*)(p + 0 * SB);
    int*   cnt_in  = (int*)(p + 1 * SB);
    int*   excl    = (int*)(p + 2 * SB);
    int*   row_ptr = (int*)(p + 3 * SB);
    int*   cursor  = (int*)(p + 4 * SB);
    float* nout    = (float*)(p + 5 * SB);
    float* nin     = (float*)(p + 6 * SB);
    int*   bsum    = (int*)(p + 7 * SB);
    float* w2p     = (float*)(p + 8 * SB);

    const int NB = (NN + 1023) / 1024;                     // 98 scan blocks
    const int AGG_BLOCKS = (NN * 64 + 255) / 256;          // one wave per node

    // ---- CSR build + norms ----
    hipMemsetAsync(cnt_out, 0, NN * 4, stream);
    hipMemsetAsync(cnt_in, 0, NN * 4, stream);
    count_k<<<2048, 256, 0, stream>>>(src, dst, cnt_out, cnt_in, NE);
    norms_k<<<(NN + 255) / 256, 256, 0, stream>>>(cnt_out, cnt_in, nout, nin, NN);
    scan1_k<<<NB, 256, 0, stream>>>(cnt_in, excl, bsum, NN);
    scan2_k<<<1, 128, 0, stream>>>(bsum, NB);
    scan3_k<<<(NN + 255) / 256, 256, 0, stream>>>(excl, bsum, row_ptr, cursor, NN);
    scatter_k<<<2048, 256, 0, stream>>>(src, dst, cursor, csr_src, NE);

    // ---- layer 0: gather(features * nout) -> tmp2; gemm -> tmp1 ----
    agg256_csr_k<1><<<AGG_BLOCKS, 256, 0, stream>>>(row_ptr, csr_src, features, nout, tmp2, NN);
    {
        dim3 grid((NN + 127) / 128, 2);
        gemm128_k<<<grid, 256, 0, stream>>>(tmp2, W0, tmp1, NN, nin, nout, b0);
    }

    // ---- layer 1: gather(tmp1) -> tmp2; gemm -> tmp1 ----
    agg256_csr_k<0><<<AGG_BLOCKS, 256, 0, stream>>>(row_ptr, csr_src, tmp1, nullptr, tmp2, NN);
    {
        dim3 grid((NN + 127) / 128, 2);
        gemm128_k<<<grid, 256, 0, stream>>>(tmp2, W1, tmp1, NN, nin, nout, b1);
    }

    // ---- layer 2: gemm (256->64 padded) -> t3; gather + epilogue -> out ----
    padw2_k<<<64, 256, 0, stream>>>(W2, w2p);
    float* t3 = tmp2;
    gemm64_k<<<(NN + 63) / 64, 256, 0, stream>>>(tmp1, w2p, t3, NN);
    agg64_csr_k<<<AGG_BLOCKS, 256, 0, stream>>>(row_ptr, csr_src, t3, nin, b2, out, NN);
}

// Round 4
// 1948.483 us; speedup vs baseline: 11.6455x; 1.0949x over previous
//
#include <hip/hip_runtime.h>

#define NN 100000
#define NE 3200000
#define F 256
#define NCLS 40

using h4 = __attribute__((ext_vector_type(4))) _Float16;
using h8 = __attribute__((ext_vector_type(8))) _Float16;
using f4 = __attribute__((ext_vector_type(4))) float;

// ---------------- degree counts (int) ----------------
__global__ void count_k(const int* __restrict__ src, const int* __restrict__ dst,
                        int* __restrict__ cnt_out, int* __restrict__ cnt_in, int nE) {
    int i = blockIdx.x * blockDim.x + threadIdx.x;
    int stride = gridDim.x * blockDim.x;
    for (; i < nE; i += stride) {
        atomicAdd(&cnt_out[src[i]], 1);
        atomicAdd(&cnt_in[dst[i]], 1);
    }
}

__global__ void norms_k(const int* __restrict__ cnt_out, const int* __restrict__ cnt_in,
                        float* __restrict__ nout, float* __restrict__ nin, int n) {
    int i = blockIdx.x * blockDim.x + threadIdx.x;
    if (i < n) {
        nout[i] = rsqrtf(fmaxf((float)cnt_out[i], 1.0f));
        nin[i]  = rsqrtf(fmaxf((float)cnt_in[i], 1.0f));
    }
}

// ---------------- exclusive scan of cnt_in -> row_ptr ----------------
__global__ __launch_bounds__(256) void scan1_k(const int* __restrict__ cin,
                                               int* __restrict__ excl,
                                               int* __restrict__ bsum, int n) {
    __shared__ int sh[256];
    int t = threadIdx.x, b = blockIdx.x;
    int base = b * 1024 + t * 4;
    int v0 = (base + 0 < n) ? cin[base + 0] : 0;
    int v1 = (base + 1 < n) ? cin[base + 1] : 0;
    int v2 = (base + 2 < n) ? cin[base + 2] : 0;
    int v3 = (base + 3 < n) ? cin[base + 3] : 0;
    int sum = v0 + v1 + v2 + v3;
    sh[t] = sum;
    __syncthreads();
    for (int off = 1; off < 256; off <<= 1) {
        int x = (t >= off) ? sh[t - off] : 0;
        __syncthreads();
        sh[t] += x;
        __syncthreads();
    }
    int tex = sh[t] - sum;
    if (base + 0 < n) excl[base + 0] = tex;
    if (base + 1 < n) excl[base + 1] = tex + v0;
    if (base + 2 < n) excl[base + 2] = tex + v0 + v1;
    if (base + 3 < n) excl[base + 3] = tex + v0 + v1 + v2;
    if (t == 255) bsum[b] = sh[255];
}

__global__ __launch_bounds__(128) void scan2_k(int* __restrict__ bsum, int nb) {
    __shared__ int sh[128];
    int t = threadIdx.x;
    int v = (t < nb) ? bsum[t] : 0;
    sh[t] = v;
    __syncthreads();
    for (int off = 1; off < 128; off <<= 1) {
        int x = (t >= off) ? sh[t - off] : 0;
        __syncthreads();
        sh[t] += x;
        __syncthreads();
    }
    if (t < nb) bsum[t] = sh[t] - v;
}

__global__ void scan3_k(const int* __restrict__ excl, const int* __restrict__ bsum,
                        int* __restrict__ row_ptr, int* __restrict__ cursor, int n) {
    int i = blockIdx.x * blockDim.x + threadIdx.x;
    if (i < n) {
        int v = excl[i] + bsum[i >> 10];
        row_ptr[i] = v;
        cursor[i] = v;
    }
    if (i == 0) row_ptr[n] = NE;
}

// ---------------- scatter edges into CSR (grouped by dst) ----------------
__global__ void scatter_k(const int* __restrict__ src, const int* __restrict__ dst,
                          int* __restrict__ cursor, int* __restrict__ csr_src, int nE) {
    int i = blockIdx.x * blockDim.x + threadIdx.x;
    int stride = gridDim.x * blockDim.x;
    for (; i < nE; i += stride) {
        int p = atomicAdd(&cursor[dst[i]], 1);
        csr_src[p] = src[i];
    }
}

// ---------------- features fp32 -> fp16, scaled by nout[row] ----------------
__global__ void convfeat_k(const float4* __restrict__ fin, const float* __restrict__ nout,
                           h4* __restrict__ fout, int n4) {
    int i = blockIdx.x * blockDim.x + threadIdx.x;
    if (i < n4) {
        float s = nout[i >> 6];     // 64 float4 per 256-float row
        float4 v = fin[i];
        h4 o;
        o[0] = (_Float16)(v.x * s);
        o[1] = (_Float16)(v.y * s);
        o[2] = (_Float16)(v.z * s);
        o[3] = (_Float16)(v.w * s);
        fout[i] = o;
    }
}

// ---------------- W [K=256][ncin] -> Wt fp16 [npad][256], zero-pad cols ----------------
__global__ void convw_k(const float* __restrict__ W, _Float16* __restrict__ Wt,
                        int ncin, int npad) {
    int i = blockIdx.x * blockDim.x + threadIdx.x;
    if (i < npad * 256) {
        int n = i >> 8, k = i & 255;
        Wt[i] = (n < ncin) ? (_Float16)W[k * ncin + n] : (_Float16)0.0f;
    }
}

// ---------------- CSR aggregation, fp16 payload, fp32 accumulate ----------------
__global__ __launch_bounds__(256) void agg256h_k(
        const int* __restrict__ row_ptr, const int* __restrict__ csr_src,
        const _Float16* __restrict__ h, _Float16* __restrict__ agg, int nN) {
    int node = (blockIdx.x * blockDim.x + threadIdx.x) >> 6;
    int lane = threadIdx.x & 63;
    if (node >= nN) return;
    int beg = row_ptr[node], end = row_ptr[node + 1];
    f4 a0 = {0.f,0.f,0.f,0.f}, a1 = {0.f,0.f,0.f,0.f};
    f4 a2 = {0.f,0.f,0.f,0.f}, a3 = {0.f,0.f,0.f,0.f};
    int e = beg;
    for (; e + 3 < end; e += 4) {
        int s0 = csr_src[e], s1 = csr_src[e+1], s2 = csr_src[e+2], s3 = csr_src[e+3];
        h4 v0 = *(const h4*)(h + (size_t)s0 * F + lane * 4);
        h4 v1 = *(const h4*)(h + (size_t)s1 * F + lane * 4);
        h4 v2 = *(const h4*)(h + (size_t)s2 * F + lane * 4);
        h4 v3 = *(const h4*)(h + (size_t)s3 * F + lane * 4);
#pragma unroll
        for (int j = 0; j < 4; j++) {
            a0[j] += (float)v0[j];
            a1[j] += (float)v1[j];
            a2[j] += (float)v2[j];
            a3[j] += (float)v3[j];
        }
    }
    for (; e < end; e++) {
        h4 v0 = *(const h4*)(h + (size_t)csr_src[e] * F + lane * 4);
#pragma unroll
        for (int j = 0; j < 4; j++) a0[j] += (float)v0[j];
    }
    h4 r;
#pragma unroll
    for (int j = 0; j < 4; j++)
        r[j] = (_Float16)((a0[j] + a1[j]) + (a2[j] + a3[j]));
    *(h4*)(agg + (size_t)node * F + lane * 4) = r;
}

// ---------------- CSR aggregation, 64-wide fp32 (layer 2) + final epilogue ----------------
__global__ __launch_bounds__(256) void agg64_csr_k(
        const int* __restrict__ row_ptr, const int* __restrict__ csr_src,
        const float* __restrict__ t3, const float* __restrict__ nin,
        const float* __restrict__ b2, float* __restrict__ out, int nN) {
    int node = (blockIdx.x * blockDim.x + threadIdx.x) >> 6;
    int lane = threadIdx.x & 63;
    if (node >= nN) return;
    int beg = row_ptr[node], end = row_ptr[node + 1];
    float a0 = 0.f, a1 = 0.f, a2 = 0.f, a3 = 0.f;
    int e = beg;
    for (; e + 3 < end; e += 4) {
        a0 += t3[(size_t)csr_src[e+0] * 64 + lane];
        a1 += t3[(size_t)csr_src[e+1] * 64 + lane];
        a2 += t3[(size_t)csr_src[e+2] * 64 + lane];
        a3 += t3[(size_t)csr_src[e+3] * 64 + lane];
    }
    for (; e < end; e++) a0 += t3[(size_t)csr_src[e] * 64 + lane];
    if (lane < NCLS)
        out[(size_t)node * NCLS + lane] = ((a0 + a1) + (a2 + a3)) * nin[node] + b2[lane];
}

// ---------------- f16 MFMA GEMM: C[M,NT*16] = A[M,256] @ Wt^T ----------------
// A fp16 row-major [M,256]; Wt fp16 [NT*16][256] (pre-transposed weight).
// Fragment pattern per verified gemm_bt lineage:
//   A-frag: row = lane&15, k = k0 + 8*(lane>>4) + j  (contiguous 16B)
//   B-frag: col = lane&15 (= Wt row), same k slice     (contiguous 16B)
//   C/D:    col = lane&15, row = 4*(lane>>4) + reg
// EPI==1: C fp16 [M,256] = relu(acc*nin[row]+bias[col]) * nout[row]
// EPI==0: C fp32 [M,64]  = acc
template <int NT, int EPI>
__global__ __launch_bounds__(256) void gemm_f16_k(
        const _Float16* __restrict__ A, const _Float16* __restrict__ Wt,
        void* __restrict__ Cout, int M,
        const float* __restrict__ nin, const float* __restrict__ nout,
        const float* __restrict__ bias) {
    int lane = threadIdx.x & 63;
    int w = threadIdx.x >> 6;
    int row0 = blockIdx.x * 64 + w * 16;
    int arow = row0 + (lane & 15);
    if (arow > M - 1) arow = M - 1;           // clamp loads; stores guarded below
    int koff = (lane >> 4) * 8;
    const _Float16* Ap = A + (size_t)arow * 256 + koff;
    const _Float16* Wp = Wt + (size_t)(lane & 15) * 256 + koff;

    f4 acc[NT];
#pragma unroll
    for (int n = 0; n < NT; n++) acc[n] = (f4){0.f, 0.f, 0.f, 0.f};

    for (int k0 = 0; k0 < 256; k0 += 32) {
        h8 af = *(const h8*)(Ap + k0);
#pragma unroll 4
        for (int n = 0; n < NT; n++) {
            h8 bf = *(const h8*)(Wp + (size_t)n * 16 * 256 + k0);
            acc[n] = __builtin_amdgcn_mfma_f32_16x16x32_f16(af, bf, acc[n], 0, 0, 0);
        }
    }

    int rbase = row0 + (lane >> 4) * 4;
    if (EPI == 1) {
        _Float16* C = (_Float16*)Cout;
        float si[4], so[4];
#pragma unroll
        for (int r = 0; r < 4; r++) {
            int rr = rbase + r;
            int rc = (rr < M) ? rr : M - 1;
            si[r] = nin[rc];
            so[r] = nout[rc];
        }
#pragma unroll
        for (int n = 0; n < NT; n++) {
            int col = n * 16 + (lane & 15);
            float bb = bias[col];
#pragma unroll
            for (int r = 0; r < 4; r++) {
                int rr = rbase + r;
                if (rr < M) {
                    float x = acc[n][r] * si[r] + bb;
                    x = fmaxf(x, 0.f) * so[r];
                    C[(size_t)rr * 256 + col] = (_Float16)x;
                }
            }
        }
    } else {
        float* C = (float*)Cout;
#pragma unroll
        for (int n = 0; n < NT; n++) {
            int col = n * 16 + (lane & 15);
#pragma unroll
            for (int r = 0; r < 4; r++) {
                int rr = rbase + r;
                if (rr < M) C[(size_t)rr * 64 + col] = acc[n][r];
            }
        }
    }
}

extern "C" void kernel_launch(void* const* d_in, const int* in_sizes, int n_in,
                              void* d_out, int out_size, void* d_ws, size_t ws_size,
                              hipStream_t stream) {
    const float* features = (const float*)d_in[0];
    const int*   src      = (const int*)d_in[1];
    const int*   dst      = (const int*)d_in[2];
    const float* W0       = (const float*)d_in[3];
    const float* b0       = (const float*)d_in[4];
    const float* W1       = (const float*)d_in[5];
    const float* b1       = (const float*)d_in[6];
    const float* W2       = (const float*)d_in[7];
    const float* b2       = (const float*)d_in[8];
    float* out = (float*)d_out;

    // ---- workspace carve (16B-aligned sections) ----
    char* ws = (char*)d_ws;
    const size_t H_BYTES = (size_t)NN * F * 2;             // 51,200,000
    _Float16* hA = (_Float16*)(ws);                        // [NN,256] fp16
    _Float16* hB = (_Float16*)(ws + H_BYTES);              // [NN,256] fp16
    float* t3    = (float*)(ws + 2 * H_BYTES);             // [NN,64] fp32 (25.6MB)
    int* csr_src = (int*)(ws + 2 * H_BYTES + (size_t)NN * 64 * 4);   // 12.8MB
    char* p = ws + 2 * H_BYTES + (size_t)NN * 64 * 4 + (size_t)NE * 4;
    const size_t SB = 401408;
    int*   cnt_out = (int*)(p + 0 * SB);
    int*   cnt_in  = (int*)(p + 1 * SB);
    int*   excl    = (int*)(p + 2 * SB);
    int*   row_ptr = (int*)(p + 3 * SB);
    int*   cursor  = (int*)(p + 4 * SB);
    float* nout    = (float*)(p + 5 * SB);
    float* nin     = (float*)(p + 6 * SB);
    int*   bsum    = (int*)(p + 7 * SB);
    _Float16* Wt0  = (_Float16*)(p + 8 * SB);              // [256][256] fp16 = 128KB
    _Float16* Wt1  = (_Float16*)(p + 8 * SB + 131072);
    _Float16* Wt2  = (_Float16*)(p + 8 * SB + 262144);     // [64][256] fp16 = 32KB

    const int NB = (NN + 1023) / 1024;
    const int AGG_BLOCKS = (NN * 64 + 255) / 256;          // one wave per node
    const int GB = (NN + 63) / 64;                         // gemm blocks (64 rows each)

    // ---- CSR build + norms ----
    hipMemsetAsync(cnt_out, 0, NN * 4, stream);
    hipMemsetAsync(cnt_in, 0, NN * 4, stream);
    count_k<<<2048, 256, 0, stream>>>(src, dst, cnt_out, cnt_in, NE);
    norms_k<<<(NN + 255) / 256, 256, 0, stream>>>(cnt_out, cnt_in, nout, nin, NN);
    scan1_k<<<NB, 256, 0, stream>>>(cnt_in, excl, bsum, NN);
    scan2_k<<<1, 128, 0, stream>>>(bsum, NB);
    scan3_k<<<(NN + 255) / 256, 256, 0, stream>>>(excl, bsum, row_ptr, cursor, NN);
    scatter_k<<<2048, 256, 0, stream>>>(src, dst, cursor, csr_src, NE);

    // ---- one-time conversions ----
    int n4 = NN * 64;
    convfeat_k<<<(n4 + 255) / 256, 256, 0, stream>>>((const float4*)features, nout,
                                                     (h4*)hB, n4);
    convw_k<<<256, 256, 0, stream>>>(W0, Wt0, 256, 256);
    convw_k<<<256, 256, 0, stream>>>(W1, Wt1, 256, 256);
    convw_k<<<64, 256, 0, stream>>>(W2, Wt2, NCLS, 64);

    // ---- layer 0 ----
    agg256h_k<<<AGG_BLOCKS, 256, 0, stream>>>(row_ptr, csr_src, hB, hA, NN);
    gemm_f16_k<16, 1><<<GB, 256, 0, stream>>>(hA, Wt0, hB, NN, nin, nout, b0);

    // ---- layer 1 ----
    agg256h_k<<<AGG_BLOCKS, 256, 0, stream>>>(row_ptr, csr_src, hB, hA, NN);
    gemm_f16_k<16, 1><<<GB, 256, 0, stream>>>(hA, Wt1, hB, NN, nin, nout, b1);

    // ---- layer 2: gemm (256->64 padded) -> t3 fp32; gather + epilogue -> out ----
    gemm_f16_k<4, 0><<<GB, 256, 0, stream>>>(hB, Wt2, t3, NN, nullptr, nullptr, nullptr);
    agg64_csr_k<<<AGG_BLOCKS, 256, 0, stream>>>(row_ptr, csr_src, t3, nin, b2, out, NN);
}

// Round 5
// 1332.814 us; speedup vs baseline: 17.0250x; 1.4619x over previous
//
#include <hip/hip_runtime.h>

#define NN 100000
#define NE 3200000
#define F 256
#define NCLS 40

using h4 = __attribute__((ext_vector_type(4))) _Float16;
using h8 = __attribute__((ext_vector_type(8))) _Float16;
using f4 = __attribute__((ext_vector_type(4))) float;

// ---------------- degree counts (int) ----------------
__global__ void count_k(const int* __restrict__ src, const int* __restrict__ dst,
                        int* __restrict__ cnt_out, int* __restrict__ cnt_in, int nE) {
    int i = blockIdx.x * blockDim.x + threadIdx.x;
    int stride = gridDim.x * blockDim.x;
    for (; i < nE; i += stride) {
        atomicAdd(&cnt_out[src[i]], 1);
        atomicAdd(&cnt_in[dst[i]], 1);
    }
}

__global__ void norms_k(const int* __restrict__ cnt_out, const int* __restrict__ cnt_in,
                        float* __restrict__ nout, float* __restrict__ nin, int n) {
    int i = blockIdx.x * blockDim.x + threadIdx.x;
    if (i < n) {
        nout[i] = rsqrtf(fmaxf((float)cnt_out[i], 1.0f));
        nin[i]  = rsqrtf(fmaxf((float)cnt_in[i], 1.0f));
    }
}

// ---------------- exclusive scan of cnt_in -> row_ptr ----------------
__global__ __launch_bounds__(256) void scan1_k(const int* __restrict__ cin,
                                               int* __restrict__ excl,
                                               int* __restrict__ bsum, int n) {
    __shared__ int sh[256];
    int t = threadIdx.x, b = blockIdx.x;
    int base = b * 1024 + t * 4;
    int v0 = (base + 0 < n) ? cin[base + 0] : 0;
    int v1 = (base + 1 < n) ? cin[base + 1] : 0;
    int v2 = (base + 2 < n) ? cin[base + 2] : 0;
    int v3 = (base + 3 < n) ? cin[base + 3] : 0;
    int sum = v0 + v1 + v2 + v3;
    sh[t] = sum;
    __syncthreads();
    for (int off = 1; off < 256; off <<= 1) {
        int x = (t >= off) ? sh[t - off] : 0;
        __syncthreads();
        sh[t] += x;
        __syncthreads();
    }
    int tex = sh[t] - sum;
    if (base + 0 < n) excl[base + 0] = tex;
    if (base + 1 < n) excl[base + 1] = tex + v0;
    if (base + 2 < n) excl[base + 2] = tex + v0 + v1;
    if (base + 3 < n) excl[base + 3] = tex + v0 + v1 + v2;
    if (t == 255) bsum[b] = sh[255];
}

__global__ __launch_bounds__(128) void scan2_k(int* __restrict__ bsum, int nb) {
    __shared__ int sh[128];
    int t = threadIdx.x;
    int v = (t < nb) ? bsum[t] : 0;
    sh[t] = v;
    __syncthreads();
    for (int off = 1; off < 128; off <<= 1) {
        int x = (t >= off) ? sh[t - off] : 0;
        __syncthreads();
        sh[t] += x;
        __syncthreads();
    }
    if (t < nb) bsum[t] = sh[t] - v;
}

__global__ void scan3_k(const int* __restrict__ excl, const int* __restrict__ bsum,
                        int* __restrict__ row_ptr, int* __restrict__ cursor, int n) {
    int i = blockIdx.x * blockDim.x + threadIdx.x;
    if (i < n) {
        int v = excl[i] + bsum[i >> 10];
        row_ptr[i] = v;
        cursor[i] = v;
    }
    if (i == 0) row_ptr[n] = NE;
}

// ---------------- scatter edges into CSR (grouped by dst) ----------------
__global__ void scatter_k(const int* __restrict__ src, const int* __restrict__ dst,
                          int* __restrict__ cursor, int* __restrict__ csr_src, int nE) {
    int i = blockIdx.x * blockDim.x + threadIdx.x;
    int stride = gridDim.x * blockDim.x;
    for (; i < nE; i += stride) {
        int p = atomicAdd(&cursor[dst[i]], 1);
        csr_src[p] = src[i];
    }
}

// ---------------- features fp32 -> fp16, scaled by nout[row] ----------------
__global__ void convfeat_k(const float4* __restrict__ fin, const float* __restrict__ nout,
                           h4* __restrict__ fout, int n4) {
    int i = blockIdx.x * blockDim.x + threadIdx.x;
    if (i < n4) {
        float s = nout[i >> 6];
        float4 v = fin[i];
        h4 o;
        o[0] = (_Float16)(v.x * s);
        o[1] = (_Float16)(v.y * s);
        o[2] = (_Float16)(v.z * s);
        o[3] = (_Float16)(v.w * s);
        fout[i] = o;
    }
}

// ---------------- W [K=256][ncin] -> Wt fp16 [npad][256], zero-pad cols ----------------
__global__ void convw_k(const float* __restrict__ W, _Float16* __restrict__ Wt,
                        int ncin, int npad) {
    int i = blockIdx.x * blockDim.x + threadIdx.x;
    if (i < npad * 256) {
        int n = i >> 8, k = i & 255;
        Wt[i] = (n < ncin) ? (_Float16)W[k * ncin + n] : (_Float16)0.0f;
    }
}

// ---------------- CSR aggregation, fp16 payload, fp32 accumulate ----------------
__global__ __launch_bounds__(256) void agg256h_k(
        const int* __restrict__ row_ptr, const int* __restrict__ csr_src,
        const _Float16* __restrict__ h, _Float16* __restrict__ agg, int nN) {
    int node = (blockIdx.x * blockDim.x + threadIdx.x) >> 6;
    int lane = threadIdx.x & 63;
    if (node >= nN) return;
    int beg = row_ptr[node], end = row_ptr[node + 1];
    f4 a0 = {0.f,0.f,0.f,0.f}, a1 = {0.f,0.f,0.f,0.f};
    f4 a2 = {0.f,0.f,0.f,0.f}, a3 = {0.f,0.f,0.f,0.f};
    int e = beg;
    for (; e + 3 < end; e += 4) {
        int s0 = csr_src[e], s1 = csr_src[e+1], s2 = csr_src[e+2], s3 = csr_src[e+3];
        h4 v0 = *(const h4*)(h + (size_t)s0 * F + lane * 4);
        h4 v1 = *(const h4*)(h + (size_t)s1 * F + lane * 4);
        h4 v2 = *(const h4*)(h + (size_t)s2 * F + lane * 4);
        h4 v3 = *(const h4*)(h + (size_t)s3 * F + lane * 4);
#pragma unroll
        for (int j = 0; j < 4; j++) {
            a0[j] += (float)v0[j];
            a1[j] += (float)v1[j];
            a2[j] += (float)v2[j];
            a3[j] += (float)v3[j];
        }
    }
    for (; e < end; e++) {
        h4 v0 = *(const h4*)(h + (size_t)csr_src[e] * F + lane * 4);
#pragma unroll
        for (int j = 0; j < 4; j++) a0[j] += (float)v0[j];
    }
    h4 r;
#pragma unroll
    for (int j = 0; j < 4; j++)
        r[j] = (_Float16)((a0[j] + a1[j]) + (a2[j] + a3[j]));
    *(h4*)(agg + (size_t)node * F + lane * 4) = r;
}

// ---------------- CSR aggregation, 64-wide fp16 (layer 2) + final epilogue ----------------
__global__ __launch_bounds__(256) void agg64h_k(
        const int* __restrict__ row_ptr, const int* __restrict__ csr_src,
        const _Float16* __restrict__ t3, const float* __restrict__ nin,
        const float* __restrict__ b2, float* __restrict__ out, int nN) {
    int node = (blockIdx.x * blockDim.x + threadIdx.x) >> 6;
    int lane = threadIdx.x & 63;
    if (node >= nN) return;
    int beg = row_ptr[node], end = row_ptr[node + 1];
    float a0 = 0.f, a1 = 0.f, a2 = 0.f, a3 = 0.f;
    int e = beg;
    for (; e + 3 < end; e += 4) {
        a0 += (float)t3[(size_t)csr_src[e+0] * 64 + lane];
        a1 += (float)t3[(size_t)csr_src[e+1] * 64 + lane];
        a2 += (float)t3[(size_t)csr_src[e+2] * 64 + lane];
        a3 += (float)t3[(size_t)csr_src[e+3] * 64 + lane];
    }
    for (; e < end; e++) a0 += (float)t3[(size_t)csr_src[e] * 64 + lane];
    if (lane < NCLS)
        out[(size_t)node * NCLS + lane] = ((a0 + a1) + (a2 + a3)) * nin[node] + b2[lane];
}

// ---------------- LDS-resident f16 MFMA GEMM ----------------
// C[M][COLS] = A[M][256] @ Wt^T, Wt fp16 [COLS][256] staged fully in LDS
// (XOR-swizzled: byte ^= (row&7)<<4 — kills stride-512B bank conflicts on
//  ds_read_b128; swizzle applied on BOTH write and read, reg-staged).
// 8 waves x 16 rows = 128 rows per block. A held in registers (8 x h8).
// C written via LDS transpose -> 1KB-contiguous dwordx4 stores (no partial-
//  sector write amplification).
// EPI==1: C = relu(acc*nin[row]+bias[col])*nout[row]; EPI==0: C = acc.
template <int NT, int EPI>
__global__ __launch_bounds__(512) void gemm_lds_k(
        const _Float16* __restrict__ A, const _Float16* __restrict__ Wt,
        _Float16* __restrict__ C, int M,
        const float* __restrict__ nin, const float* __restrict__ nout,
        const float* __restrict__ bias) {
    constexpr int COLS = NT * 16;
    __shared__ _Float16 lds[COLS * 256];     // NT=16: 128 KiB, NT=4: 32 KiB
    char* ldsb = (char*)lds;

    const int tid  = threadIdx.x;
    const int lane = tid & 63;
    const int w    = tid >> 6;               // wave 0..7
    const int row0 = blockIdx.x * 128;

    // ---- stage Wt -> LDS (swizzled), linear global reads ----
#pragma unroll
    for (int i = 0; i < COLS / 16; i++) {
        int idx  = (i * 512 + tid) * 8;      // half index
        int byte = idx * 2;
        int row  = byte >> 9;                // /512
        int swz  = byte ^ ((row & 7) << 4);
        h8 v = *(const h8*)(Wt + idx);
        *(h8*)(ldsb + swz) = v;
    }

    // ---- A row slice -> registers (8 x h8 = full K) ----
    int arow = row0 + w * 16 + (lane & 15);
    if (arow >= M) arow = M - 1;
    const _Float16* Ap = A + (size_t)arow * 256 + (lane >> 4) * 8;
    h8 areg[8];
#pragma unroll
    for (int i = 0; i < 8; i++) areg[i] = *(const h8*)(Ap + i * 32);

    __syncthreads();

    // ---- k-loop: pure LDS + MFMA ----
    f4 acc[NT];
#pragma unroll
    for (int n = 0; n < NT; n++) acc[n] = (f4){0.f, 0.f, 0.f, 0.f};

#pragma unroll
    for (int k0 = 0; k0 < 8; k0++) {
        int kb = (k0 * 32 + (lane >> 4) * 8) * 2;   // byte offset in row
#pragma unroll
        for (int n = 0; n < NT; n++) {
            int r    = n * 16 + (lane & 15);
            int byte = r * 512 + kb;
            int swz  = byte ^ ((r & 7) << 4);
            h8 bf = *(const h8*)(ldsb + swz);
            acc[n] = __builtin_amdgcn_mfma_f32_16x16x32_f16(areg[k0], bf, acc[n], 0, 0, 0);
        }
    }

    __syncthreads();   // all waves done reading Wt; reuse LDS for C transpose

    // ---- epilogue + transpose through LDS ----
    const int g  = lane >> 4;
    const int rb = row0 + w * 16 + g * 4;
    float si[4], so[4];
    if (EPI) {
#pragma unroll
        for (int r = 0; r < 4; r++) {
            int rr = rb + r; if (rr >= M) rr = M - 1;
            si[r] = nin[rr];
            so[r] = nout[rr];
        }
    }
    char* warea = ldsb + w * (16 * COLS * 2);   // private 16-row fp16 tile
#pragma unroll
    for (int n = 0; n < NT; n++) {
        float bb = EPI ? bias[n * 16 + (lane & 15)] : 0.f;
#pragma unroll
        for (int r = 0; r < 4; r++) {
            float x = acc[n][r];
            if (EPI) x = fmaxf(x * si[r] + bb, 0.f) * so[r];
            int lrow = g * 4 + r;
            int lcol = n * 16 + (lane & 15);
            *(_Float16*)(warea + (size_t)(lrow * COLS + lcol) * 2) = (_Float16)x;
        }
    }
    // wave-private area: only lgkmcnt ordering needed (compiler inserts)

    _Float16* Crow = C + (size_t)(row0 + w * 16) * COLS;
#pragma unroll
    for (int i = 0; i < COLS / 32; i++) {        // 16*COLS*2 / 1024 iters
        int off  = i * 1024 + lane * 16;
        int lrow = off / (COLS * 2);
        int grow = row0 + w * 16 + lrow;
        h8 v = *(const h8*)(warea + off);
        if (grow < M) *(h8*)((char*)Crow + off) = v;
    }
}

extern "C" void kernel_launch(void* const* d_in, const int* in_sizes, int n_in,
                              void* d_out, int out_size, void* d_ws, size_t ws_size,
                              hipStream_t stream) {
    const float* features = (const float*)d_in[0];
    const int*   src      = (const int*)d_in[1];
    const int*   dst      = (const int*)d_in[2];
    const float* W0       = (const float*)d_in[3];
    const float* b0       = (const float*)d_in[4];
    const float* W1       = (const float*)d_in[5];
    const float* b1       = (const float*)d_in[6];
    const float* W2       = (const float*)d_in[7];
    const float* b2       = (const float*)d_in[8];
    float* out = (float*)d_out;

    // ---- workspace carve (16B-aligned sections) ----
    char* ws = (char*)d_ws;
    const size_t H_BYTES = (size_t)NN * F * 2;             // 51,200,000
    _Float16* hA  = (_Float16*)(ws);                       // [NN,256] fp16
    _Float16* hB  = (_Float16*)(ws + H_BYTES);             // [NN,256] fp16
    _Float16* t3h = (_Float16*)(ws + 2 * H_BYTES);         // [NN,64] fp16 (12.8MB)
    int* csr_src  = (int*)(ws + 2 * H_BYTES + (size_t)NN * 64 * 2);
    char* p = ws + 2 * H_BYTES + (size_t)NN * 64 * 2 + (size_t)NE * 4;
    const size_t SB = 401408;
    int*   cnt_out = (int*)(p + 0 * SB);
    int*   cnt_in  = (int*)(p + 1 * SB);
    int*   excl    = (int*)(p + 2 * SB);
    int*   row_ptr = (int*)(p + 3 * SB);
    int*   cursor  = (int*)(p + 4 * SB);
    float* nout    = (float*)(p + 5 * SB);
    float* nin     = (float*)(p + 6 * SB);
    int*   bsum    = (int*)(p + 7 * SB);
    _Float16* Wt0  = (_Float16*)(p + 8 * SB);              // [256][256] fp16 = 128KB
    _Float16* Wt1  = (_Float16*)(p + 8 * SB + 131072);
    _Float16* Wt2  = (_Float16*)(p + 8 * SB + 262144);     // [64][256] fp16 = 32KB

    const int NB = (NN + 1023) / 1024;
    const int AGG_BLOCKS = (NN * 64 + 255) / 256;          // one wave per node
    const int GB = (NN + 127) / 128;                       // 782 gemm blocks

    // ---- CSR build + norms ----
    hipMemsetAsync(cnt_out, 0, NN * 4, stream);
    hipMemsetAsync(cnt_in, 0, NN * 4, stream);
    count_k<<<2048, 256, 0, stream>>>(src, dst, cnt_out, cnt_in, NE);
    norms_k<<<(NN + 255) / 256, 256, 0, stream>>>(cnt_out, cnt_in, nout, nin, NN);
    scan1_k<<<NB, 256, 0, stream>>>(cnt_in, excl, bsum, NN);
    scan2_k<<<1, 128, 0, stream>>>(bsum, NB);
    scan3_k<<<(NN + 255) / 256, 256, 0, stream>>>(excl, bsum, row_ptr, cursor, NN);
    scatter_k<<<2048, 256, 0, stream>>>(src, dst, cursor, csr_src, NE);

    // ---- one-time conversions ----
    int n4 = NN * 64;
    convfeat_k<<<(n4 + 255) / 256, 256, 0, stream>>>((const float4*)features, nout,
                                                     (h4*)hB, n4);
    convw_k<<<256, 256, 0, stream>>>(W0, Wt0, 256, 256);
    convw_k<<<256, 256, 0, stream>>>(W1, Wt1, 256, 256);
    convw_k<<<64, 256, 0, stream>>>(W2, Wt2, NCLS, 64);

    // ---- layer 0 ----
    agg256h_k<<<AGG_BLOCKS, 256, 0, stream>>>(row_ptr, csr_src, hB, hA, NN);
    gemm_lds_k<16, 1><<<GB, 512, 0, stream>>>(hA, Wt0, hB, NN, nin, nout, b0);

    // ---- layer 1 ----
    agg256h_k<<<AGG_BLOCKS, 256, 0, stream>>>(row_ptr, csr_src, hB, hA, NN);
    gemm_lds_k<16, 1><<<GB, 512, 0, stream>>>(hA, Wt1, hB, NN, nin, nout, b1);

    // ---- layer 2: gemm (256->64 padded) -> t3h fp16; gather + epilogue -> out ----
    gemm_lds_k<4, 0><<<GB, 512, 0, stream>>>(hB, Wt2, t3h, NN, nullptr, nullptr, nullptr);
    agg64h_k<<<AGG_BLOCKS, 256, 0, stream>>>(row_ptr, csr_src, t3h, nin, b2, out, NN);
}

// Round 6
// 1278.599 us; speedup vs baseline: 17.7469x; 1.0424x over previous
//
#include <hip/hip_runtime.h>

#define NN 100000
#define NE 3200000
#define F 256
#define NCLS 40
#define NBKT 12500          // buckets of 8 dst nodes each: 12500*8 == NN

using h4 = __attribute__((ext_vector_type(4))) _Float16;
using h8 = __attribute__((ext_vector_type(8))) _Float16;
using f4 = __attribute__((ext_vector_type(4))) float;

// ---------------- fused histogram: out-degree + dst-bucket counts ----------------
__global__ void hist_k(const int* __restrict__ src, const int* __restrict__ dst,
                       int* __restrict__ cnt_out, int* __restrict__ bcnt, int nE) {
    int i = blockIdx.x * blockDim.x + threadIdx.x;
    int stride = gridDim.x * blockDim.x;
    for (; i < nE; i += stride) {
        atomicAdd(&cnt_out[src[i]], 1);
        atomicAdd(&bcnt[dst[i] >> 3], 1);
    }
}

__global__ void nout_k(const int* __restrict__ cnt_out, float* __restrict__ nout, int n) {
    int i = blockIdx.x * blockDim.x + threadIdx.x;
    if (i < n) nout[i] = rsqrtf(fmaxf((float)cnt_out[i], 1.0f));
}

// ---------------- exclusive scan (bucket counts) ----------------
__global__ __launch_bounds__(256) void scan1_k(const int* __restrict__ cin,
                                               int* __restrict__ excl,
                                               int* __restrict__ bsum, int n) {
    __shared__ int sh[256];
    int t = threadIdx.x, b = blockIdx.x;
    int base = b * 1024 + t * 4;
    int v0 = (base + 0 < n) ? cin[base + 0] : 0;
    int v1 = (base + 1 < n) ? cin[base + 1] : 0;
    int v2 = (base + 2 < n) ? cin[base + 2] : 0;
    int v3 = (base + 3 < n) ? cin[base + 3] : 0;
    int sum = v0 + v1 + v2 + v3;
    sh[t] = sum;
    __syncthreads();
    for (int off = 1; off < 256; off <<= 1) {
        int x = (t >= off) ? sh[t - off] : 0;
        __syncthreads();
        sh[t] += x;
        __syncthreads();
    }
    int tex = sh[t] - sum;
    if (base + 0 < n) excl[base + 0] = tex;
    if (base + 1 < n) excl[base + 1] = tex + v0;
    if (base + 2 < n) excl[base + 2] = tex + v0 + v1;
    if (base + 3 < n) excl[base + 3] = tex + v0 + v1 + v2;
    if (t == 255) bsum[b] = sh[255];
}

__global__ __launch_bounds__(128) void scan2_k(int* __restrict__ bsum, int nb) {
    __shared__ int sh[128];
    int t = threadIdx.x;
    int v = (t < nb) ? bsum[t] : 0;
    sh[t] = v;
    __syncthreads();
    for (int off = 1; off < 128; off <<= 1) {
        int x = (t >= off) ? sh[t - off] : 0;
        __syncthreads();
        sh[t] += x;
        __syncthreads();
    }
    if (t < nb) bsum[t] = sh[t] - v;
}

__global__ void scan3b_k(const int* __restrict__ excl, const int* __restrict__ bsum,
                         int* __restrict__ boff, int* __restrict__ bcur, int n) {
    int i = blockIdx.x * blockDim.x + threadIdx.x;
    if (i < n) {
        int v = excl[i] + bsum[i >> 10];
        boff[i] = v;
        bcur[i] = v;
    }
    if (i == 0) boff[n] = NE;
}

// ---------------- scatter edges into bucket regions (packed u32) ----------------
// pack: src (17 bits) | (dst&7) << 17
__global__ void scatb_k(const int* __restrict__ src, const int* __restrict__ dst,
                        int* __restrict__ bcur, unsigned* __restrict__ ebuf, int nE) {
    int i = blockIdx.x * blockDim.x + threadIdx.x;
    int stride = gridDim.x * blockDim.x;
    for (; i < nE; i += stride) {
        int d = dst[i];
        int p = atomicAdd(&bcur[d >> 3], 1);
        ebuf[p] = (unsigned)src[i] | ((unsigned)(d & 7) << 17);
    }
}

// ---------------- per-bucket CSR segment build (coalesced writes) ----------------
// one 64-thread block per bucket (8 dst nodes); emits csr_src, row_ptr, nin
__global__ __launch_bounds__(64) void build_k(
        const int* __restrict__ boff, const unsigned* __restrict__ ebuf,
        int* __restrict__ csr_src, int* __restrict__ row_ptr,
        float* __restrict__ nin) {
    __shared__ int cnt[8], cur[8];
    int b = blockIdx.x, t = threadIdx.x;
    int beg = boff[b], end = boff[b + 1];
    if (t < 8) cnt[t] = 0;
    __syncthreads();
    for (int e = beg + t; e < end; e += 64)
        atomicAdd(&cnt[(ebuf[e] >> 17) & 7], 1);
    __syncthreads();
    if (t == 0) {
        int run = beg;
#pragma unroll
        for (int n = 0; n < 8; n++) { cur[n] = run; run += cnt[n]; }
    }
    __syncthreads();
    if (t < 8) {
        row_ptr[b * 8 + t] = cur[t];
        nin[b * 8 + t] = rsqrtf(fmaxf((float)cnt[t], 1.0f));
    }
    if (b == 0 && t == 0) row_ptr[NN] = NE;
    __syncthreads();                 // row_ptr reads of cur[] complete before mutation
    for (int e = beg + t; e < end; e += 64) {
        unsigned v = ebuf[e];
        int p = atomicAdd(&cur[(v >> 17) & 7], 1);
        csr_src[p] = (int)(v & 0x1FFFFu);
    }
}

// ---------------- features fp32 -> fp16, scaled by nout[row] ----------------
__global__ void convfeat_k(const float4* __restrict__ fin, const float* __restrict__ nout,
                           h4* __restrict__ fout, int n4) {
    int i = blockIdx.x * blockDim.x + threadIdx.x;
    if (i < n4) {
        float s = nout[i >> 6];
        float4 v = fin[i];
        h4 o;
        o[0] = (_Float16)(v.x * s);
        o[1] = (_Float16)(v.y * s);
        o[2] = (_Float16)(v.z * s);
        o[3] = (_Float16)(v.w * s);
        fout[i] = o;
    }
}

// ---------------- W [K=256][ncin] -> Wt fp16 [npad][256], zero-pad cols ----------------
__global__ void convw_k(const float* __restrict__ W, _Float16* __restrict__ Wt,
                        int ncin, int npad) {
    int i = blockIdx.x * blockDim.x + threadIdx.x;
    if (i < npad * 256) {
        int n = i >> 8, k = i & 255;
        Wt[i] = (n < ncin) ? (_Float16)W[k * ncin + n] : (_Float16)0.0f;
    }
}

// ---------------- CSR aggregation, fp16 payload, fp32 accumulate, 8-deep MLP ----------------
__global__ __launch_bounds__(256) void agg256h_k(
        const int* __restrict__ row_ptr, const int* __restrict__ csr_src,
        const _Float16* __restrict__ h, _Float16* __restrict__ agg, int nN) {
    int node = (blockIdx.x * blockDim.x + threadIdx.x) >> 6;
    int lane = threadIdx.x & 63;
    if (node >= nN) return;
    int beg = row_ptr[node], end = row_ptr[node + 1];
    f4 a[8];
#pragma unroll
    for (int u = 0; u < 8; u++) a[u] = (f4){0.f, 0.f, 0.f, 0.f};
    int e = beg;
    for (; e + 7 < end; e += 8) {
        int s[8];
#pragma unroll
        for (int u = 0; u < 8; u++) s[u] = csr_src[e + u];
        h4 v[8];
#pragma unroll
        for (int u = 0; u < 8; u++)
            v[u] = *(const h4*)(h + (size_t)s[u] * F + lane * 4);
#pragma unroll
        for (int u = 0; u < 8; u++)
#pragma unroll
            for (int j = 0; j < 4; j++) a[u][j] += (float)v[u][j];
    }
    for (; e + 1 < end; e += 2) {
        int s0 = csr_src[e], s1 = csr_src[e + 1];
        h4 v0 = *(const h4*)(h + (size_t)s0 * F + lane * 4);
        h4 v1 = *(const h4*)(h + (size_t)s1 * F + lane * 4);
#pragma unroll
        for (int j = 0; j < 4; j++) { a[0][j] += (float)v0[j]; a[1][j] += (float)v1[j]; }
    }
    if (e < end) {
        h4 v0 = *(const h4*)(h + (size_t)csr_src[e] * F + lane * 4);
#pragma unroll
        for (int j = 0; j < 4; j++) a[0][j] += (float)v0[j];
    }
    h4 r;
#pragma unroll
    for (int j = 0; j < 4; j++) {
        float s = ((a[0][j] + a[1][j]) + (a[2][j] + a[3][j]))
                + ((a[4][j] + a[5][j]) + (a[6][j] + a[7][j]));
        r[j] = (_Float16)s;
    }
    *(h4*)(agg + (size_t)node * F + lane * 4) = r;
}

// ---------------- CSR aggregation, 64-wide fp16 (layer 2) + final epilogue ----------------
__global__ __launch_bounds__(256) void agg64h_k(
        const int* __restrict__ row_ptr, const int* __restrict__ csr_src,
        const _Float16* __restrict__ t3, const float* __restrict__ nin,
        const float* __restrict__ b2, float* __restrict__ out, int nN) {
    int node = (blockIdx.x * blockDim.x + threadIdx.x) >> 6;
    int lane = threadIdx.x & 63;
    if (node >= nN) return;
    int beg = row_ptr[node], end = row_ptr[node + 1];
    float a0 = 0.f, a1 = 0.f, a2 = 0.f, a3 = 0.f;
    int e = beg;
    for (; e + 3 < end; e += 4) {
        a0 += (float)t3[(size_t)csr_src[e+0] * 64 + lane];
        a1 += (float)t3[(size_t)csr_src[e+1] * 64 + lane];
        a2 += (float)t3[(size_t)csr_src[e+2] * 64 + lane];
        a3 += (float)t3[(size_t)csr_src[e+3] * 64 + lane];
    }
    for (; e < end; e++) a0 += (float)t3[(size_t)csr_src[e] * 64 + lane];
    if (lane < NCLS)
        out[(size_t)node * NCLS + lane] = ((a0 + a1) + (a2 + a3)) * nin[node] + b2[lane];
}

// ---------------- LDS-resident f16 MFMA GEMM (unchanged from round 5) ----------------
template <int NT, int EPI>
__global__ __launch_bounds__(512) void gemm_lds_k(
        const _Float16* __restrict__ A, const _Float16* __restrict__ Wt,
        _Float16* __restrict__ C, int M,
        const float* __restrict__ nin, const float* __restrict__ nout,
        const float* __restrict__ bias) {
    constexpr int COLS = NT * 16;
    __shared__ _Float16 lds[COLS * 256];
    char* ldsb = (char*)lds;

    const int tid  = threadIdx.x;
    const int lane = tid & 63;
    const int w    = tid >> 6;
    const int row0 = blockIdx.x * 128;

#pragma unroll
    for (int i = 0; i < COLS / 16; i++) {
        int idx  = (i * 512 + tid) * 8;
        int byte = idx * 2;
        int row  = byte >> 9;
        int swz  = byte ^ ((row & 7) << 4);
        h8 v = *(const h8*)(Wt + idx);
        *(h8*)(ldsb + swz) = v;
    }

    int arow = row0 + w * 16 + (lane & 15);
    if (arow >= M) arow = M - 1;
    const _Float16* Ap = A + (size_t)arow * 256 + (lane >> 4) * 8;
    h8 areg[8];
#pragma unroll
    for (int i = 0; i < 8; i++) areg[i] = *(const h8*)(Ap + i * 32);

    __syncthreads();

    f4 acc[NT];
#pragma unroll
    for (int n = 0; n < NT; n++) acc[n] = (f4){0.f, 0.f, 0.f, 0.f};

#pragma unroll
    for (int k0 = 0; k0 < 8; k0++) {
        int kb = (k0 * 32 + (lane >> 4) * 8) * 2;
#pragma unroll
        for (int n = 0; n < NT; n++) {
            int r    = n * 16 + (lane & 15);
            int byte = r * 512 + kb;
            int swz  = byte ^ ((r & 7) << 4);
            h8 bf = *(const h8*)(ldsb + swz);
            acc[n] = __builtin_amdgcn_mfma_f32_16x16x32_f16(areg[k0], bf, acc[n], 0, 0, 0);
        }
    }

    __syncthreads();

    const int g  = lane >> 4;
    const int rb = row0 + w * 16 + g * 4;
    float si[4], so[4];
    if (EPI) {
#pragma unroll
        for (int r = 0; r < 4; r++) {
            int rr = rb + r; if (rr >= M) rr = M - 1;
            si[r] = nin[rr];
            so[r] = nout[rr];
        }
    }
    char* warea = ldsb + w * (16 * COLS * 2);
#pragma unroll
    for (int n = 0; n < NT; n++) {
        float bb = EPI ? bias[n * 16 + (lane & 15)] : 0.f;
#pragma unroll
        for (int r = 0; r < 4; r++) {
            float x = acc[n][r];
            if (EPI) x = fmaxf(x * si[r] + bb, 0.f) * so[r];
            int lrow = g * 4 + r;
            int lcol = n * 16 + (lane & 15);
            *(_Float16*)(warea + (size_t)(lrow * COLS + lcol) * 2) = (_Float16)x;
        }
    }

    _Float16* Crow = C + (size_t)(row0 + w * 16) * COLS;
#pragma unroll
    for (int i = 0; i < COLS / 32; i++) {
        int off  = i * 1024 + lane * 16;
        int lrow = off / (COLS * 2);
        int grow = row0 + w * 16 + lrow;
        h8 v = *(const h8*)(warea + off);
        if (grow < M) *(h8*)((char*)Crow + off) = v;
    }
}

extern "C" void kernel_launch(void* const* d_in, const int* in_sizes, int n_in,
                              void* d_out, int out_size, void* d_ws, size_t ws_size,
                              hipStream_t stream) {
    const float* features = (const float*)d_in[0];
    const int*   src      = (const int*)d_in[1];
    const int*   dst      = (const int*)d_in[2];
    const float* W0       = (const float*)d_in[3];
    const float* b0       = (const float*)d_in[4];
    const float* W1       = (const float*)d_in[5];
    const float* b1       = (const float*)d_in[6];
    const float* W2       = (const float*)d_in[7];
    const float* b2       = (const float*)d_in[8];
    float* out = (float*)d_out;

    // ---- workspace carve (16B-aligned sections) ----
    char* ws = (char*)d_ws;
    const size_t H_BYTES = (size_t)NN * F * 2;             // 51,200,000
    _Float16* hA  = (_Float16*)(ws);                       // [NN,256] fp16
    _Float16* hB  = (_Float16*)(ws + H_BYTES);             // [NN,256] fp16
    _Float16* t3h = (_Float16*)(ws + 2 * H_BYTES);         // [NN,64] fp16
    int* csr_src  = (int*)(ws + 2 * H_BYTES + (size_t)NN * 64 * 2);       // 12.8MB
    unsigned* ebuf = (unsigned*)(ws + 2 * H_BYTES + (size_t)NN * 64 * 2
                                 + (size_t)NE * 4);                       // 12.8MB
    char* p = ws + 2 * H_BYTES + (size_t)NN * 64 * 2 + 2 * (size_t)NE * 4;
    const size_t SB = 401408;
    int*   cnt_out = (int*)(p + 0 * SB);
    int*   bcnt    = (int*)(p + 1 * SB);                   // NBKT ints
    int*   excl    = (int*)(p + 2 * SB);                   // NBKT ints
    int*   row_ptr = (int*)(p + 3 * SB);                   // NN+1 ints
    int*   boff    = (int*)(p + 4 * SB);                   // NBKT+1 ints
    float* nout    = (float*)(p + 5 * SB);
    float* nin     = (float*)(p + 6 * SB);
    int*   bsum    = (int*)(p + 7 * SB);
    int*   bcur    = (int*)(p + 8 * SB);                   // NBKT ints
    _Float16* Wt0  = (_Float16*)(p + 9 * SB);              // 128KB
    _Float16* Wt1  = (_Float16*)(p + 9 * SB + 131072);
    _Float16* Wt2  = (_Float16*)(p + 9 * SB + 262144);     // 32KB

    const int NBB = (NBKT + 1023) / 1024;                  // 13 scan blocks
    const int AGG_BLOCKS = (NN * 64 + 255) / 256;
    const int GB = (NN + 127) / 128;

    // ---- CSR build (bucketed counting sort) + norms ----
    hipMemsetAsync(cnt_out, 0, NN * 4, stream);
    hipMemsetAsync(bcnt, 0, NBKT * 4, stream);
    hist_k<<<2048, 256, 0, stream>>>(src, dst, cnt_out, bcnt, NE);
    nout_k<<<(NN + 255) / 256, 256, 0, stream>>>(cnt_out, nout, NN);
    scan1_k<<<NBB, 256, 0, stream>>>(bcnt, excl, bsum, NBKT);
    scan2_k<<<1, 128, 0, stream>>>(bsum, NBB);
    scan3b_k<<<(NBKT + 255) / 256, 256, 0, stream>>>(excl, bsum, boff, bcur, NBKT);
    scatb_k<<<2048, 256, 0, stream>>>(src, dst, bcur, ebuf, NE);
    build_k<<<NBKT, 64, 0, stream>>>(boff, ebuf, csr_src, row_ptr, nin);

    // ---- one-time conversions ----
    int n4 = NN * 64;
    convfeat_k<<<(n4 + 255) / 256, 256, 0, stream>>>((const float4*)features, nout,
                                                     (h4*)hB, n4);
    convw_k<<<256, 256, 0, stream>>>(W0, Wt0, 256, 256);
    convw_k<<<256, 256, 0, stream>>>(W1, Wt1, 256, 256);
    convw_k<<<64, 256, 0, stream>>>(W2, Wt2, NCLS, 64);

    // ---- layer 0 ----
    agg256h_k<<<AGG_BLOCKS, 256, 0, stream>>>(row_ptr, csr_src, hB, hA, NN);
    gemm_lds_k<16, 1><<<GB, 512, 0, stream>>>(hA, Wt0, hB, NN, nin, nout, b0);

    // ---- layer 1 ----
    agg256h_k<<<AGG_BLOCKS, 256, 0, stream>>>(row_ptr, csr_src, hB, hA, NN);
    gemm_lds_k<16, 1><<<GB, 512, 0, stream>>>(hA, Wt1, hB, NN, nin, nout, b1);

    // ---- layer 2: gemm (256->64 padded) -> t3h fp16; gather + epilogue -> out ----
    gemm_lds_k<4, 0><<<GB, 512, 0, stream>>>(hB, Wt2, t3h, NN, nullptr, nullptr, nullptr);
    agg64h_k<<<AGG_BLOCKS, 256, 0, stream>>>(row_ptr, csr_src, t3h, nin, b2, out, NN);
}

// Round 7
// 1066.284 us; speedup vs baseline: 21.2806x; 1.1991x over previous
//
#include <hip/hip_runtime.h>

#define NN 100000
#define NE 3200000
#define F 256
#define NCLS 40
#define NBKT 12500          // buckets of 8 dst nodes each: 12500*8 == NN
#define NBLK_H 256          // histogram blocks (1 per CU); NE/NBLK_H = 12500
#define CW 25000            // cnt_out words (NN/4, byte-packed)

using h4 = __attribute__((ext_vector_type(4))) _Float16;
using h8 = __attribute__((ext_vector_type(8))) _Float16;
using f4 = __attribute__((ext_vector_type(4))) float;

// ---------------- LDS-privatized histogram: out-degree (u8-packed) + dst buckets ----------------
__global__ __launch_bounds__(256) void hist_k(const int* __restrict__ src,
                                              const int* __restrict__ dst,
                                              unsigned* __restrict__ pcnt,
                                              unsigned* __restrict__ pbcnt) {
    __shared__ unsigned hsrc[CW];     // 100 KB: per-node u8 counts, 4 nodes/word
    __shared__ unsigned hb[NBKT];     // 50 KB
    int t = threadIdx.x, b = blockIdx.x;
    for (int i = t; i < CW; i += 256) hsrc[i] = 0;
    for (int i = t; i < NBKT; i += 256) hb[i] = 0;
    __syncthreads();
    int beg = b * (NE / NBLK_H), end = beg + NE / NBLK_H;
    for (int e = beg + t; e < end; e += 256) {
        int s = src[e];
        atomicAdd(&hsrc[s >> 2], 1u << (8 * (s & 3)));
        atomicAdd(&hb[dst[e] >> 3], 1u);
    }
    __syncthreads();
    unsigned* pc = pcnt + (size_t)b * CW;
    for (int i = t; i < CW; i += 256) pc[i] = hsrc[i];
    unsigned* pb = pbcnt + (size_t)b * NBKT;
    for (int i = t; i < NBKT; i += 256) pb[i] = hb[i];
}

// ---------------- reduce partials -> nout (4 nodes per thread) ----------------
__global__ void rednout_k(const unsigned* __restrict__ pcnt, float* __restrict__ nout) {
    int w = blockIdx.x * blockDim.x + threadIdx.x;
    if (w >= CW) return;
    unsigned s0 = 0, s1 = 0, s2 = 0, s3 = 0;
    for (int b = 0; b < NBLK_H; b++) {
        unsigned v = pcnt[(size_t)b * CW + w];
        s0 += v & 255u; s1 += (v >> 8) & 255u; s2 += (v >> 16) & 255u; s3 += v >> 24;
    }
    float4 o;
    o.x = rsqrtf(fmaxf((float)s0, 1.f));
    o.y = rsqrtf(fmaxf((float)s1, 1.f));
    o.z = rsqrtf(fmaxf((float)s2, 1.f));
    o.w = rsqrtf(fmaxf((float)s3, 1.f));
    *(float4*)(nout + w * 4) = o;
}

// ---------------- reduce partials -> bcnt ----------------
__global__ void redbcnt_k(const unsigned* __restrict__ pbcnt, int* __restrict__ bcnt) {
    int w = blockIdx.x * blockDim.x + threadIdx.x;
    if (w >= NBKT) return;
    unsigned s = 0;
    for (int b = 0; b < NBLK_H; b++) s += pbcnt[(size_t)b * NBKT + w];
    bcnt[w] = (int)s;
}

// ---------------- exclusive scan (bucket counts) ----------------
__global__ __launch_bounds__(256) void scan1_k(const int* __restrict__ cin,
                                               int* __restrict__ excl,
                                               int* __restrict__ bsum, int n) {
    __shared__ int sh[256];
    int t = threadIdx.x, b = blockIdx.x;
    int base = b * 1024 + t * 4;
    int v0 = (base + 0 < n) ? cin[base + 0] : 0;
    int v1 = (base + 1 < n) ? cin[base + 1] : 0;
    int v2 = (base + 2 < n) ? cin[base + 2] : 0;
    int v3 = (base + 3 < n) ? cin[base + 3] : 0;
    int sum = v0 + v1 + v2 + v3;
    sh[t] = sum;
    __syncthreads();
    for (int off = 1; off < 256; off <<= 1) {
        int x = (t >= off) ? sh[t - off] : 0;
        __syncthreads();
        sh[t] += x;
        __syncthreads();
    }
    int tex = sh[t] - sum;
    if (base + 0 < n) excl[base + 0] = tex;
    if (base + 1 < n) excl[base + 1] = tex + v0;
    if (base + 2 < n) excl[base + 2] = tex + v0 + v1;
    if (base + 3 < n) excl[base + 3] = tex + v0 + v1 + v2;
    if (t == 255) bsum[b] = sh[255];
}

__global__ __launch_bounds__(128) void scan2_k(int* __restrict__ bsum, int nb) {
    __shared__ int sh[128];
    int t = threadIdx.x;
    int v = (t < nb) ? bsum[t] : 0;
    sh[t] = v;
    __syncthreads();
    for (int off = 1; off < 128; off <<= 1) {
        int x = (t >= off) ? sh[t - off] : 0;
        __syncthreads();
        sh[t] += x;
        __syncthreads();
    }
    if (t < nb) bsum[t] = sh[t] - v;
}

__global__ void scan3b_k(const int* __restrict__ excl, const int* __restrict__ bsum,
                         int* __restrict__ boff, int* __restrict__ bcur, int n) {
    int i = blockIdx.x * blockDim.x + threadIdx.x;
    if (i < n) {
        int v = excl[i] + bsum[i >> 10];
        boff[i] = v;
        bcur[i] = v;
    }
    if (i == 0) boff[n] = NE;
}

// ---------------- scatter edges into bucket regions (packed u32) ----------------
__global__ void scatb_k(const int* __restrict__ src, const int* __restrict__ dst,
                        int* __restrict__ bcur, unsigned* __restrict__ ebuf, int nE) {
    int i = blockIdx.x * blockDim.x + threadIdx.x;
    int stride = gridDim.x * blockDim.x;
    for (; i < nE; i += stride) {
        int d = dst[i];
        int p = atomicAdd(&bcur[d >> 3], 1);
        ebuf[p] = (unsigned)src[i] | ((unsigned)(d & 7) << 17);
    }
}

// ---------------- per-bucket CSR segment build ----------------
__global__ __launch_bounds__(64) void build_k(
        const int* __restrict__ boff, const unsigned* __restrict__ ebuf,
        int* __restrict__ csr_src, int* __restrict__ row_ptr,
        float* __restrict__ nin) {
    __shared__ int cnt[8], cur[8];
    int b = blockIdx.x, t = threadIdx.x;
    int beg = boff[b], end = boff[b + 1];
    if (t < 8) cnt[t] = 0;
    __syncthreads();
    for (int e = beg + t; e < end; e += 64)
        atomicAdd(&cnt[(ebuf[e] >> 17) & 7], 1);
    __syncthreads();
    if (t == 0) {
        int run = beg;
#pragma unroll
        for (int n = 0; n < 8; n++) { cur[n] = run; run += cnt[n]; }
    }
    __syncthreads();
    if (t < 8) {
        row_ptr[b * 8 + t] = cur[t];
        nin[b * 8 + t] = rsqrtf(fmaxf((float)cnt[t], 1.0f));
    }
    if (b == 0 && t == 0) row_ptr[NN] = NE;
    __syncthreads();
    for (int e = beg + t; e < end; e += 64) {
        unsigned v = ebuf[e];
        int p = atomicAdd(&cur[(v >> 17) & 7], 1);
        csr_src[p] = (int)(v & 0x1FFFFu);
    }
}

// ---------------- features fp32 -> fp16, scaled by nout[row] ----------------
__global__ void convfeat_k(const float4* __restrict__ fin, const float* __restrict__ nout,
                           h4* __restrict__ fout, int n4) {
    int i = blockIdx.x * blockDim.x + threadIdx.x;
    if (i < n4) {
        float s = nout[i >> 6];
        float4 v = fin[i];
        h4 o;
        o[0] = (_Float16)(v.x * s);
        o[1] = (_Float16)(v.y * s);
        o[2] = (_Float16)(v.z * s);
        o[3] = (_Float16)(v.w * s);
        fout[i] = o;
    }
}

// ---------------- W [K=256][ncin] -> Wt fp16 [npad][256], zero-pad cols ----------------
__global__ void convw_k(const float* __restrict__ W, _Float16* __restrict__ Wt,
                        int ncin, int npad) {
    int i = blockIdx.x * blockDim.x + threadIdx.x;
    if (i < npad * 256) {
        int n = i >> 8, k = i & 255;
        Wt[i] = (n < ncin) ? (_Float16)W[k * ncin + n] : (_Float16)0.0f;
    }
}

// ---------------- CSR aggregation, 256-wide: 32 lanes/edge, h8 loads, 2x4 deep ----------------
__global__ __launch_bounds__(256) void agg256h_k(
        const int* __restrict__ row_ptr, const int* __restrict__ csr_src,
        const _Float16* __restrict__ h, _Float16* __restrict__ agg, int nN) {
    int node = (blockIdx.x * blockDim.x + threadIdx.x) >> 6;
    int lane = threadIdx.x & 63;
    if (node >= nN) return;
    int half = lane >> 5, col = lane & 31;        // col owns halfs col*8..col*8+7
    int beg = row_ptr[node], end = row_ptr[node + 1];
    f4 a[4][2];
#pragma unroll
    for (int u = 0; u < 4; u++) { a[u][0] = (f4){0,0,0,0}; a[u][1] = (f4){0,0,0,0}; }
    int e = beg;
    for (; e + 7 < end; e += 8) {                 // 8 edges/iter, 4 per half
        int s[4];
#pragma unroll
        for (int u = 0; u < 4; u++) s[u] = csr_src[e + 2 * u + half];
        h8 v[4];
#pragma unroll
        for (int u = 0; u < 4; u++)
            v[u] = *(const h8*)(h + (size_t)s[u] * F + col * 8);
#pragma unroll
        for (int u = 0; u < 4; u++)
#pragma unroll
            for (int j = 0; j < 8; j++) a[u][j >> 2][j & 3] += (float)v[u][j];
    }
    for (int t = e + half; t < end; t += 2) {     // tail: halves alternate edges
        h8 v = *(const h8*)(h + (size_t)csr_src[t] * F + col * 8);
#pragma unroll
        for (int j = 0; j < 8; j++) a[0][j >> 2][j & 3] += (float)v[j];
    }
    float r[8];
#pragma unroll
    for (int j = 0; j < 8; j++)
        r[j] = (a[0][j >> 2][j & 3] + a[1][j >> 2][j & 3])
             + (a[2][j >> 2][j & 3] + a[3][j >> 2][j & 3]);
#pragma unroll
    for (int j = 0; j < 8; j++) r[j] += __shfl_xor(r[j], 32);
    if (half == 0) {
        h8 o;
#pragma unroll
        for (int j = 0; j < 8; j++) o[j] = (_Float16)r[j];
        *(h8*)(agg + (size_t)node * F + col * 8) = o;
    }
}

// ---------------- CSR aggregation, 64-wide: 16 lanes/edge + final epilogue ----------------
__global__ __launch_bounds__(256) void agg64h_k(
        const int* __restrict__ row_ptr, const int* __restrict__ csr_src,
        const _Float16* __restrict__ t3, const float* __restrict__ nin,
        const float* __restrict__ b2, float* __restrict__ out, int nN) {
    int node = (blockIdx.x * blockDim.x + threadIdx.x) >> 6;
    int lane = threadIdx.x & 63;
    if (node >= nN) return;
    int q = lane >> 4, c = lane & 15;             // c owns halfs c*4..c*4+3
    int beg = row_ptr[node], end = row_ptr[node + 1];
    f4 a0 = {0,0,0,0}, a1 = {0,0,0,0};
    int e = beg;
    for (; e + 7 < end; e += 8) {                 // 8 edges/iter, 2 per quarter
        int s0 = csr_src[e + q], s1 = csr_src[e + 4 + q];
        h4 v0 = *(const h4*)(t3 + (size_t)s0 * 64 + c * 4);
        h4 v1 = *(const h4*)(t3 + (size_t)s1 * 64 + c * 4);
#pragma unroll
        for (int j = 0; j < 4; j++) { a0[j] += (float)v0[j]; a1[j] += (float)v1[j]; }
    }
    for (int t = e + q; t < end; t += 4) {
        h4 v = *(const h4*)(t3 + (size_t)csr_src[t] * 64 + c * 4);
#pragma unroll
        for (int j = 0; j < 4; j++) a0[j] += (float)v[j];
    }
    float r[4];
#pragma unroll
    for (int j = 0; j < 4; j++) {
        r[j] = a0[j] + a1[j];
        r[j] += __shfl_xor(r[j], 16);
        r[j] += __shfl_xor(r[j], 32);
    }
    if (lane < 10) {                              // cols lane*4..lane*4+3 < 40
        float ni = nin[node];
        float4 o;
        o.x = r[0] * ni + b2[lane * 4 + 0];
        o.y = r[1] * ni + b2[lane * 4 + 1];
        o.z = r[2] * ni + b2[lane * 4 + 2];
        o.w = r[3] * ni + b2[lane * 4 + 3];
        *(float4*)(out + (size_t)node * NCLS + lane * 4) = o;
    }
}

// ---------------- LDS-resident f16 MFMA GEMM (unchanged) ----------------
template <int NT, int EPI>
__global__ __launch_bounds__(512) void gemm_lds_k(
        const _Float16* __restrict__ A, const _Float16* __restrict__ Wt,
        _Float16* __restrict__ C, int M,
        const float* __restrict__ nin, const float* __restrict__ nout,
        const float* __restrict__ bias) {
    constexpr int COLS = NT * 16;
    __shared__ _Float16 lds[COLS * 256];
    char* ldsb = (char*)lds;

    const int tid  = threadIdx.x;
    const int lane = tid & 63;
    const int w    = tid >> 6;
    const int row0 = blockIdx.x * 128;

#pragma unroll
    for (int i = 0; i < COLS / 16; i++) {
        int idx  = (i * 512 + tid) * 8;
        int byte = idx * 2;
        int row  = byte >> 9;
        int swz  = byte ^ ((row & 7) << 4);
        h8 v = *(const h8*)(Wt + idx);
        *(h8*)(ldsb + swz) = v;
    }

    int arow = row0 + w * 16 + (lane & 15);
    if (arow >= M) arow = M - 1;
    const _Float16* Ap = A + (size_t)arow * 256 + (lane >> 4) * 8;
    h8 areg[8];
#pragma unroll
    for (int i = 0; i < 8; i++) areg[i] = *(const h8*)(Ap + i * 32);

    __syncthreads();

    f4 acc[NT];
#pragma unroll
    for (int n = 0; n < NT; n++) acc[n] = (f4){0.f, 0.f, 0.f, 0.f};

#pragma unroll
    for (int k0 = 0; k0 < 8; k0++) {
        int kb = (k0 * 32 + (lane >> 4) * 8) * 2;
#pragma unroll
        for (int n = 0; n < NT; n++) {
            int r    = n * 16 + (lane & 15);
            int byte = r * 512 + kb;
            int swz  = byte ^ ((r & 7) << 4);
            h8 bf = *(const h8*)(ldsb + swz);
            acc[n] = __builtin_amdgcn_mfma_f32_16x16x32_f16(areg[k0], bf, acc[n], 0, 0, 0);
        }
    }

    __syncthreads();

    const int g  = lane >> 4;
    const int rb = row0 + w * 16 + g * 4;
    float si[4], so[4];
    if (EPI) {
#pragma unroll
        for (int r = 0; r < 4; r++) {
            int rr = rb + r; if (rr >= M) rr = M - 1;
            si[r] = nin[rr];
            so[r] = nout[rr];
        }
    }
    char* warea = ldsb + w * (16 * COLS * 2);
#pragma unroll
    for (int n = 0; n < NT; n++) {
        float bb = EPI ? bias[n * 16 + (lane & 15)] : 0.f;
#pragma unroll
        for (int r = 0; r < 4; r++) {
            float x = acc[n][r];
            if (EPI) x = fmaxf(x * si[r] + bb, 0.f) * so[r];
            int lrow = g * 4 + r;
            int lcol = n * 16 + (lane & 15);
            *(_Float16*)(warea + (size_t)(lrow * COLS + lcol) * 2) = (_Float16)x;
        }
    }

    _Float16* Crow = C + (size_t)(row0 + w * 16) * COLS;
#pragma unroll
    for (int i = 0; i < COLS / 32; i++) {
        int off  = i * 1024 + lane * 16;
        int lrow = off / (COLS * 2);
        int grow = row0 + w * 16 + lrow;
        h8 v = *(const h8*)(warea + off);
        if (grow < M) *(h8*)((char*)Crow + off) = v;
    }
}

extern "C" void kernel_launch(void* const* d_in, const int* in_sizes, int n_in,
                              void* d_out, int out_size, void* d_ws, size_t ws_size,
                              hipStream_t stream) {
    const float* features = (const float*)d_in[0];
    const int*   src      = (const int*)d_in[1];
    const int*   dst      = (const int*)d_in[2];
    const float* W0       = (const float*)d_in[3];
    const float* b0       = (const float*)d_in[4];
    const float* W1       = (const float*)d_in[5];
    const float* b1       = (const float*)d_in[6];
    const float* W2       = (const float*)d_in[7];
    const float* b2       = (const float*)d_in[8];
    float* out = (float*)d_out;

    // ---- workspace carve (16B-aligned sections) ----
    char* ws = (char*)d_ws;
    const size_t H_BYTES = (size_t)NN * F * 2;             // 51.2 MB
    _Float16* hA   = (_Float16*)(ws);
    _Float16* hB   = (_Float16*)(ws + H_BYTES);
    _Float16* t3h  = (_Float16*)(ws + 2 * H_BYTES);        // [NN,64] fp16
    char* q = ws + 2 * H_BYTES + (size_t)NN * 64 * 2;
    int* csr_src   = (int*)q;                q += (size_t)NE * 4;        // 12.8 MB
    unsigned* ebuf = (unsigned*)q;           q += (size_t)NE * 4;        // 12.8 MB
    unsigned* pcnt = (unsigned*)q;           q += (size_t)NBLK_H * CW * 4;    // 25.6 MB
    unsigned* pbcnt= (unsigned*)q;           q += (size_t)NBLK_H * NBKT * 4;  // 12.8 MB
    char* p = q;
    const size_t SB = 401408;
    int*   bcnt    = (int*)(p + 0 * SB);
    int*   excl    = (int*)(p + 1 * SB);
    int*   row_ptr = (int*)(p + 2 * SB);
    int*   boff    = (int*)(p + 3 * SB);
    float* nout    = (float*)(p + 4 * SB);
    float* nin     = (float*)(p + 5 * SB);
    int*   bsum    = (int*)(p + 6 * SB);
    int*   bcur    = (int*)(p + 7 * SB);
    _Float16* Wt0  = (_Float16*)(p + 8 * SB);              // 128 KB
    _Float16* Wt1  = (_Float16*)(p + 8 * SB + 131072);
    _Float16* Wt2  = (_Float16*)(p + 8 * SB + 262144);     // 32 KB

    const int NBB = (NBKT + 1023) / 1024;                  // 13 scan blocks
    const int AGG_BLOCKS = (NN * 64 + 255) / 256;
    const int GB = (NN + 127) / 128;

    // ---- CSR build (LDS histogram + bucketed counting sort) ----
    hist_k<<<NBLK_H, 256, 0, stream>>>(src, dst, pcnt, pbcnt);
    rednout_k<<<(CW + 255) / 256, 256, 0, stream>>>(pcnt, nout);
    redbcnt_k<<<(NBKT + 255) / 256, 256, 0, stream>>>(pbcnt, bcnt);
    scan1_k<<<NBB, 256, 0, stream>>>(bcnt, excl, bsum, NBKT);
    scan2_k<<<1, 128, 0, stream>>>(bsum, NBB);
    scan3b_k<<<(NBKT + 255) / 256, 256, 0, stream>>>(excl, bsum, boff, bcur, NBKT);
    scatb_k<<<2048, 256, 0, stream>>>(src, dst, bcur, ebuf, NE);
    build_k<<<NBKT, 64, 0, stream>>>(boff, ebuf, csr_src, row_ptr, nin);

    // ---- one-time conversions ----
    int n4 = NN * 64;
    convfeat_k<<<(n4 + 255) / 256, 256, 0, stream>>>((const float4*)features, nout,
                                                     (h4*)hB, n4);
    convw_k<<<256, 256, 0, stream>>>(W0, Wt0, 256, 256);
    convw_k<<<256, 256, 0, stream>>>(W1, Wt1, 256, 256);
    convw_k<<<64, 256, 0, stream>>>(W2, Wt2, NCLS, 64);

    // ---- layer 0 ----
    agg256h_k<<<AGG_BLOCKS, 256, 0, stream>>>(row_ptr, csr_src, hB, hA, NN);
    gemm_lds_k<16, 1><<<GB, 512, 0, stream>>>(hA, Wt0, hB, NN, nin, nout, b0);

    // ---- layer 1 ----
    agg256h_k<<<AGG_BLOCKS, 256, 0, stream>>>(row_ptr, csr_src, hB, hA, NN);
    gemm_lds_k<16, 1><<<GB, 512, 0, stream>>>(hA, Wt1, hB, NN, nin, nout, b1);

    // ---- layer 2 ----
    gemm_lds_k<4, 0><<<GB, 512, 0, stream>>>(hB, Wt2, t3h, NN, nullptr, nullptr, nullptr);
    agg64h_k<<<AGG_BLOCKS, 256, 0, stream>>>(row_ptr, csr_src, t3h, nin, b2, out, NN);
}

// Round 8
// 918.023 us; speedup vs baseline: 24.7174x; 1.1615x over previous
//
#include <hip/hip_runtime.h>

#define NN 100000
#define NE 3200000
#define F 256
#define NCLS 40
#define NC 391              // coarse buckets of 256 dst nodes: 391*256 >= NN
#define NBLK_H 256          // histogram/scatter blocks (1 per CU); NE/NBLK_H = 12500
#define EPB (NE / NBLK_H)   // 12500 edges per block slice
#define CW 25000            // cnt_out words (NN/4, byte-packed)

using h4 = __attribute__((ext_vector_type(4))) _Float16;
using h8 = __attribute__((ext_vector_type(8))) _Float16;
using f4 = __attribute__((ext_vector_type(4))) float;

// ---------------- LDS-privatized histogram: out-degree (u8-packed) + coarse dst buckets ----------------
__global__ __launch_bounds__(256) void hist_k(const int* __restrict__ src,
                                              const int* __restrict__ dst,
                                              unsigned* __restrict__ pcnt,
                                              unsigned* __restrict__ pcc) {
    __shared__ unsigned hsrc[CW];     // 100 KB: per-node u8 counts, 4 nodes/word
    __shared__ unsigned hc[NC];       // 1.6 KB coarse bucket counts
    int t = threadIdx.x, b = blockIdx.x;
    for (int i = t; i < CW; i += 256) hsrc[i] = 0;
    for (int i = t; i < NC; i += 256) hc[i] = 0;
    __syncthreads();
    int beg = b * EPB, end = beg + EPB;
    for (int e = beg + t; e < end; e += 256) {
        int s = src[e];
        atomicAdd(&hsrc[s >> 2], 1u << (8 * (s & 3)));
        atomicAdd(&hc[dst[e] >> 8], 1u);
    }
    __syncthreads();
    unsigned* pc = pcnt + (size_t)b * CW;
    for (int i = t; i < CW; i += 256) pc[i] = hsrc[i];
    unsigned* pb = pcc + (size_t)b * NC;
    for (int i = t; i < NC; i += 256) pb[i] = hc[i];
}

// ---------------- reduce partials -> nout (4 nodes per thread) ----------------
__global__ void rednout_k(const unsigned* __restrict__ pcnt, float* __restrict__ nout) {
    int w = blockIdx.x * blockDim.x + threadIdx.x;
    if (w >= CW) return;
    unsigned s0 = 0, s1 = 0, s2 = 0, s3 = 0;
    for (int b = 0; b < NBLK_H; b++) {
        unsigned v = pcnt[(size_t)b * CW + w];
        s0 += v & 255u; s1 += (v >> 8) & 255u; s2 += (v >> 16) & 255u; s3 += v >> 24;
    }
    float4 o;
    o.x = rsqrtf(fmaxf((float)s0, 1.f));
    o.y = rsqrtf(fmaxf((float)s1, 1.f));
    o.z = rsqrtf(fmaxf((float)s2, 1.f));
    o.w = rsqrtf(fmaxf((float)s3, 1.f));
    *(float4*)(nout + w * 4) = o;
}

// ---------------- per-bucket scan over blocks: curoff[b][c] = sum_{b'<b} pcc[b'][c] ----------------
__global__ __launch_bounds__(256) void offsets_k(const unsigned* __restrict__ pcc,
                                                 unsigned* __restrict__ curoff,
                                                 unsigned* __restrict__ totals) {
    __shared__ unsigned sh[256];
    int c = blockIdx.x, t = threadIdx.x;
    unsigned v = pcc[(size_t)t * NC + c];
    sh[t] = v;
    __syncthreads();
    for (int off = 1; off < 256; off <<= 1) {
        unsigned x = (t >= off) ? sh[t - off] : 0;
        __syncthreads();
        sh[t] += x;
        __syncthreads();
    }
    curoff[(size_t)t * NC + c] = sh[t] - v;   // exclusive over blocks
    if (t == 255) totals[c] = sh[255];
}

// ---------------- exclusive scan of coarse totals -> cbase[NC+1] ----------------
__global__ __launch_bounds__(512) void base_k(const unsigned* __restrict__ totals,
                                              int* __restrict__ cbase) {
    __shared__ unsigned sh[512];
    int t = threadIdx.x;
    unsigned v = (t < NC) ? totals[t] : 0;
    sh[t] = v;
    __syncthreads();
    for (int off = 1; off < 512; off <<= 1) {
        unsigned x = (t >= off) ? sh[t - off] : 0;
        __syncthreads();
        sh[t] += x;
        __syncthreads();
    }
    if (t < NC) cbase[t] = (int)(sh[t] - v);
    if (t == 0) cbase[NC] = NE;
}

// ---------------- pass 1: scatter edges into coarse regions, LDS cursors, no global atomics ----------------
// pack: src (17 bits) | (dst & 255) << 17
__global__ __launch_bounds__(256) void p1scat_k(const int* __restrict__ src,
                                                const int* __restrict__ dst,
                                                const int* __restrict__ cbase,
                                                const unsigned* __restrict__ curoff,
                                                unsigned* __restrict__ ebuf) {
    __shared__ int cur[NC];
    int t = threadIdx.x, b = blockIdx.x;
    for (int i = t; i < NC; i += 256)
        cur[i] = cbase[i] + (int)curoff[(size_t)b * NC + i];
    __syncthreads();
    int beg = b * EPB, end = beg + EPB;
    for (int e = beg + t; e < end; e += 256) {
        int d = dst[e];
        int p = atomicAdd(&cur[d >> 8], 1);
        ebuf[p] = (unsigned)src[e] | ((unsigned)(d & 255) << 17);
    }
}

// ---------------- pass 2: per-coarse-bucket fine sort -> csr_src, row_ptr, nin ----------------
__global__ __launch_bounds__(256) void p2build_k(const int* __restrict__ cbase,
                                                 const unsigned* __restrict__ ebuf,
                                                 int* __restrict__ csr_src,
                                                 int* __restrict__ row_ptr,
                                                 float* __restrict__ nin) {
    __shared__ int cnt[256], cur[256], sh[256];
    int c = blockIdx.x, t = threadIdx.x;
    int beg = cbase[c], end = cbase[c + 1];
    cnt[t] = 0;
    __syncthreads();
    for (int e = beg + t; e < end; e += 256)
        atomicAdd(&cnt[(ebuf[e] >> 17) & 255], 1);
    __syncthreads();
    int v = cnt[t];
    sh[t] = v;
    __syncthreads();
    for (int off = 1; off < 256; off <<= 1) {
        int x = (t >= off) ? sh[t - off] : 0;
        __syncthreads();
        sh[t] += x;
        __syncthreads();
    }
    int pref = sh[t] - v;                 // exclusive prefix within bucket
    int node = c * 256 + t;
    if (node <= NN) row_ptr[node] = beg + pref;   // node==NN lands here (c=390,t=160)
    if (node < NN)  nin[node] = rsqrtf(fmaxf((float)v, 1.f));
    cur[t] = pref;
    __syncthreads();
    for (int e = beg + t; e < end; e += 256) {
        unsigned w = ebuf[e];
        int p = atomicAdd(&cur[(w >> 17) & 255], 1);
        csr_src[beg + p] = (int)(w & 0x1FFFFu);
    }
}

// ---------------- features fp32 -> fp16, scaled by nout[row] ----------------
__global__ void convfeat_k(const float4* __restrict__ fin, const float* __restrict__ nout,
                           h4* __restrict__ fout, int n4) {
    int i = blockIdx.x * blockDim.x + threadIdx.x;
    if (i < n4) {
        float s = nout[i >> 6];
        float4 v = fin[i];
        h4 o;
        o[0] = (_Float16)(v.x * s);
        o[1] = (_Float16)(v.y * s);
        o[2] = (_Float16)(v.z * s);
        o[3] = (_Float16)(v.w * s);
        fout[i] = o;
    }
}

// ---------------- W [K=256][ncin] -> Wt fp16 [npad][256], zero-pad cols ----------------
__global__ void convw_k(const float* __restrict__ W, _Float16* __restrict__ Wt,
                        int ncin, int npad) {
    int i = blockIdx.x * blockDim.x + threadIdx.x;
    if (i < npad * 256) {
        int n = i >> 8, k = i & 255;
        Wt[i] = (n < ncin) ? (_Float16)W[k * ncin + n] : (_Float16)0.0f;
    }
}

// ---------------- CSR aggregation, 256-wide: 32 lanes/edge, h8 loads, 2x4 deep ----------------
__global__ __launch_bounds__(256) void agg256h_k(
        const int* __restrict__ row_ptr, const int* __restrict__ csr_src,
        const _Float16* __restrict__ h, _Float16* __restrict__ agg, int nN) {
    int node = (blockIdx.x * blockDim.x + threadIdx.x) >> 6;
    int lane = threadIdx.x & 63;
    if (node >= nN) return;
    int half = lane >> 5, col = lane & 31;
    int beg = row_ptr[node], end = row_ptr[node + 1];
    f4 a[4][2];
#pragma unroll
    for (int u = 0; u < 4; u++) { a[u][0] = (f4){0,0,0,0}; a[u][1] = (f4){0,0,0,0}; }
    int e = beg;
    for (; e + 7 < end; e += 8) {
        int s[4];
#pragma unroll
        for (int u = 0; u < 4; u++) s[u] = csr_src[e + 2 * u + half];
        h8 v[4];
#pragma unroll
        for (int u = 0; u < 4; u++)
            v[u] = *(const h8*)(h + (size_t)s[u] * F + col * 8);
#pragma unroll
        for (int u = 0; u < 4; u++)
#pragma unroll
            for (int j = 0; j < 8; j++) a[u][j >> 2][j & 3] += (float)v[u][j];
    }
    for (int t = e + half; t < end; t += 2) {
        h8 v = *(const h8*)(h + (size_t)csr_src[t] * F + col * 8);
#pragma unroll
        for (int j = 0; j < 8; j++) a[0][j >> 2][j & 3] += (float)v[j];
    }
    float r[8];
#pragma unroll
    for (int j = 0; j < 8; j++)
        r[j] = (a[0][j >> 2][j & 3] + a[1][j >> 2][j & 3])
             + (a[2][j >> 2][j & 3] + a[3][j >> 2][j & 3]);
#pragma unroll
    for (int j = 0; j < 8; j++) r[j] += __shfl_xor(r[j], 32);
    if (half == 0) {
        h8 o;
#pragma unroll
        for (int j = 0; j < 8; j++) o[j] = (_Float16)r[j];
        *(h8*)(agg + (size_t)node * F + col * 8) = o;
    }
}

// ---------------- CSR aggregation, 64-wide: 16 lanes/edge + final epilogue ----------------
__global__ __launch_bounds__(256) void agg64h_k(
        const int* __restrict__ row_ptr, const int* __restrict__ csr_src,
        const _Float16* __restrict__ t3, const float* __restrict__ nin,
        const float* __restrict__ b2, float* __restrict__ out, int nN) {
    int node = (blockIdx.x * blockDim.x + threadIdx.x) >> 6;
    int lane = threadIdx.x & 63;
    if (node >= nN) return;
    int q = lane >> 4, c = lane & 15;
    int beg = row_ptr[node], end = row_ptr[node + 1];
    f4 a0 = {0,0,0,0}, a1 = {0,0,0,0};
    int e = beg;
    for (; e + 7 < end; e += 8) {
        int s0 = csr_src[e + q], s1 = csr_src[e + 4 + q];
        h4 v0 = *(const h4*)(t3 + (size_t)s0 * 64 + c * 4);
        h4 v1 = *(const h4*)(t3 + (size_t)s1 * 64 + c * 4);
#pragma unroll
        for (int j = 0; j < 4; j++) { a0[j] += (float)v0[j]; a1[j] += (float)v1[j]; }
    }
    for (int t = e + q; t < end; t += 4) {
        h4 v = *(const h4*)(t3 + (size_t)csr_src[t] * 64 + c * 4);
#pragma unroll
        for (int j = 0; j < 4; j++) a0[j] += (float)v[j];
    }
    float r[4];
#pragma unroll
    for (int j = 0; j < 4; j++) {
        r[j] = a0[j] + a1[j];
        r[j] += __shfl_xor(r[j], 16);
        r[j] += __shfl_xor(r[j], 32);
    }
    if (lane < 10) {
        float ni = nin[node];
        float4 o;
        o.x = r[0] * ni + b2[lane * 4 + 0];
        o.y = r[1] * ni + b2[lane * 4 + 1];
        o.z = r[2] * ni + b2[lane * 4 + 2];
        o.w = r[3] * ni + b2[lane * 4 + 3];
        *(float4*)(out + (size_t)node * NCLS + lane * 4) = o;
    }
}

// ---------------- LDS-resident f16 MFMA GEMM (unchanged) ----------------
template <int NT, int EPI>
__global__ __launch_bounds__(512) void gemm_lds_k(
        const _Float16* __restrict__ A, const _Float16* __restrict__ Wt,
        _Float16* __restrict__ C, int M,
        const float* __restrict__ nin, const float* __restrict__ nout,
        const float* __restrict__ bias) {
    constexpr int COLS = NT * 16;
    __shared__ _Float16 lds[COLS * 256];
    char* ldsb = (char*)lds;

    const int tid  = threadIdx.x;
    const int lane = tid & 63;
    const int w    = tid >> 6;
    const int row0 = blockIdx.x * 128;

#pragma unroll
    for (int i = 0; i < COLS / 16; i++) {
        int idx  = (i * 512 + tid) * 8;
        int byte = idx * 2;
        int row  = byte >> 9;
        int swz  = byte ^ ((row & 7) << 4);
        h8 v = *(const h8*)(Wt + idx);
        *(h8*)(ldsb + swz) = v;
    }

    int arow = row0 + w * 16 + (lane & 15);
    if (arow >= M) arow = M - 1;
    const _Float16* Ap = A + (size_t)arow * 256 + (lane >> 4) * 8;
    h8 areg[8];
#pragma unroll
    for (int i = 0; i < 8; i++) areg[i] = *(const h8*)(Ap + i * 32);

    __syncthreads();

    f4 acc[NT];
#pragma unroll
    for (int n = 0; n < NT; n++) acc[n] = (f4){0.f, 0.f, 0.f, 0.f};

#pragma unroll
    for (int k0 = 0; k0 < 8; k0++) {
        int kb = (k0 * 32 + (lane >> 4) * 8) * 2;
#pragma unroll
        for (int n = 0; n < NT; n++) {
            int r    = n * 16 + (lane & 15);
            int byte = r * 512 + kb;
            int swz  = byte ^ ((r & 7) << 4);
            h8 bf = *(const h8*)(ldsb + swz);
            acc[n] = __builtin_amdgcn_mfma_f32_16x16x32_f16(areg[k0], bf, acc[n], 0, 0, 0);
        }
    }

    __syncthreads();

    const int g  = lane >> 4;
    const int rb = row0 + w * 16 + g * 4;
    float si[4], so[4];
    if (EPI) {
#pragma unroll
        for (int r = 0; r < 4; r++) {
            int rr = rb + r; if (rr >= M) rr = M - 1;
            si[r] = nin[rr];
            so[r] = nout[rr];
        }
    }
    char* warea = ldsb + w * (16 * COLS * 2);
#pragma unroll
    for (int n = 0; n < NT; n++) {
        float bb = EPI ? bias[n * 16 + (lane & 15)] : 0.f;
#pragma unroll
        for (int r = 0; r < 4; r++) {
            float x = acc[n][r];
            if (EPI) x = fmaxf(x * si[r] + bb, 0.f) * so[r];
            int lrow = g * 4 + r;
            int lcol = n * 16 + (lane & 15);
            *(_Float16*)(warea + (size_t)(lrow * COLS + lcol) * 2) = (_Float16)x;
        }
    }

    _Float16* Crow = C + (size_t)(row0 + w * 16) * COLS;
#pragma unroll
    for (int i = 0; i < COLS / 32; i++) {
        int off  = i * 1024 + lane * 16;
        int lrow = off / (COLS * 2);
        int grow = row0 + w * 16 + lrow;
        h8 v = *(const h8*)(warea + off);
        if (grow < M) *(h8*)((char*)Crow + off) = v;
    }
}

extern "C" void kernel_launch(void* const* d_in, const int* in_sizes, int n_in,
                              void* d_out, int out_size, void* d_ws, size_t ws_size,
                              hipStream_t stream) {
    const float* features = (const float*)d_in[0];
    const int*   src      = (const int*)d_in[1];
    const int*   dst      = (const int*)d_in[2];
    const float* W0       = (const float*)d_in[3];
    const float* b0       = (const float*)d_in[4];
    const float* W1       = (const float*)d_in[5];
    const float* b1       = (const float*)d_in[6];
    const float* W2       = (const float*)d_in[7];
    const float* b2       = (const float*)d_in[8];
    float* out = (float*)d_out;

    // ---- workspace carve (16B-aligned sections) ----
    char* ws = (char*)d_ws;
    const size_t H_BYTES = (size_t)NN * F * 2;             // 51.2 MB
    _Float16* hA   = (_Float16*)(ws);
    _Float16* hB   = (_Float16*)(ws + H_BYTES);
    _Float16* t3h  = (_Float16*)(ws + 2 * H_BYTES);        // [NN,64] fp16
    char* q = ws + 2 * H_BYTES + (size_t)NN * 64 * 2;
    int* csr_src    = (int*)q;               q += (size_t)NE * 4;             // 12.8 MB
    unsigned* ebuf  = (unsigned*)q;          q += (size_t)NE * 4;             // 12.8 MB
    unsigned* pcnt  = (unsigned*)q;          q += (size_t)NBLK_H * CW * 4;    // 25.6 MB
    unsigned* pcc   = (unsigned*)q;          q += (size_t)NBLK_H * NC * 4 + 1024;  // 400 KB
    unsigned* curoff= (unsigned*)q;          q += (size_t)NBLK_H * NC * 4 + 1024;  // 400 KB
    char* p = q;
    const size_t SB = 401408;
    unsigned* totals = (unsigned*)(p + 0 * SB);            // NC
    int*   cbase   = (int*)(p + 1 * SB);                   // NC+1
    int*   row_ptr = (int*)(p + 2 * SB);                   // NN+1
    float* nout    = (float*)(p + 3 * SB);
    float* nin     = (float*)(p + 4 * SB);
    _Float16* Wt0  = (_Float16*)(p + 5 * SB);              // 128 KB
    _Float16* Wt1  = (_Float16*)(p + 5 * SB + 131072);
    _Float16* Wt2  = (_Float16*)(p + 5 * SB + 262144);     // 32 KB

    const int AGG_BLOCKS = (NN * 64 + 255) / 256;
    const int GB = (NN + 127) / 128;

    // ---- CSR build: LDS histograms -> offset scans -> 2-pass radix, zero global atomics ----
    hist_k<<<NBLK_H, 256, 0, stream>>>(src, dst, pcnt, pcc);
    rednout_k<<<(CW + 255) / 256, 256, 0, stream>>>(pcnt, nout);
    offsets_k<<<NC, 256, 0, stream>>>(pcc, curoff, totals);
    base_k<<<1, 512, 0, stream>>>(totals, cbase);
    p1scat_k<<<NBLK_H, 256, 0, stream>>>(src, dst, cbase, curoff, ebuf);
    p2build_k<<<NC, 256, 0, stream>>>(cbase, ebuf, csr_src, row_ptr, nin);

    // ---- one-time conversions ----
    int n4 = NN * 64;
    convfeat_k<<<(n4 + 255) / 256, 256, 0, stream>>>((const float4*)features, nout,
                                                     (h4*)hB, n4);
    convw_k<<<256, 256, 0, stream>>>(W0, Wt0, 256, 256);
    convw_k<<<256, 256, 0, stream>>>(W1, Wt1, 256, 256);
    convw_k<<<64, 256, 0, stream>>>(W2, Wt2, NCLS, 64);

    // ---- layer 0 ----
    agg256h_k<<<AGG_BLOCKS, 256, 0, stream>>>(row_ptr, csr_src, hB, hA, NN);
    gemm_lds_k<16, 1><<<GB, 512, 0, stream>>>(hA, Wt0, hB, NN, nin, nout, b0);

    // ---- layer 1 ----
    agg256h_k<<<AGG_BLOCKS, 256, 0, stream>>>(row_ptr, csr_src, hB, hA, NN);
    gemm_lds_k<16, 1><<<GB, 512, 0, stream>>>(hA, Wt1, hB, NN, nin, nout, b1);

    // ---- layer 2 ----
    gemm_lds_k<4, 0><<<GB, 512, 0, stream>>>(hB, Wt2, t3h, NN, nullptr, nullptr, nullptr);
    agg64h_k<<<AGG_BLOCKS, 256, 0, stream>>>(row_ptr, csr_src, t3h, nin, b2, out, NN);
}